// Round 1
// baseline (1765.487 us; speedup 1.0000x reference)
//
#include <hip/hip_runtime.h>
#include <math.h>

// ---------------------------------------------------------------------------
// PiTWithCoords: position-attention transformer on fixed grids.
// Key facts exploited:
//  * m_dist is EXACT in fp32: m_dist = d_int / 2^S with d_int an integer
//    (down: d=(2qx-kx)^2+(2qy-ky)^2, S=13; proc: (qx-kx)^2+(qy-ky)^2, S=11;
//     up: (qx-2kx)^2+(qy-2ky)^2, S=13).
//  * percentile mask == integer threshold on d_int (scale>0 factors out):
//    down keeps d<=v[81] of 4096, proc keeps d<=v[102] of 1024 (0-indexed
//    order stats; interpolation frac 0.9/0.3 never reaches the next value).
//  * att is input-independent -> generate weights on the fly; fuse softmax
//    denominator into the contraction.
// All compute fp32 (no fp32 MFMA on CDNA4; tolerance ~2% of max|ref|).
// ---------------------------------------------------------------------------

#define PI_F 3.14159265358979323846f

__device__ __forceinline__ float gelu_f(float x) {
  // jax.nn.gelu approximate=True (tanh form)
  float x3 = x * x * x;
  return 0.5f * x * (1.0f + tanhf(0.7978845608028654f * (x + 0.044715f * x3)));
}

__device__ __forceinline__ float head_scale(float r) {
  return tanf(0.25f * PI_F * (1.0f - 1e-7f) * (1.0f + sinf(r)));
}

// ---------------------------------------------------------------------------
// Encoder: out[row,o] = gelu(sum_i x[row,i]*W[o,i] + b[o]), row in [0,32768)
// ---------------------------------------------------------------------------
__global__ __launch_bounds__(256) void k_enc(const float* __restrict__ x,
                                             const float* __restrict__ w,
                                             const float* __restrict__ b,
                                             float* __restrict__ out) {
  int row = blockIdx.x;
  int o = threadIdx.x;
  float4 xv = *(const float4*)(x + (size_t)row * 4);
  float4 wv = *(const float4*)(w + (size_t)o * 4);
  float s = xv.x * wv.x + xv.y * wv.y + xv.z * wv.z + xv.w * wv.w + b[o];
  out[(size_t)row * 256 + o] = gelu_f(s);
}

// ---------------------------------------------------------------------------
// Integer-threshold (order statistic) per query row via binary search count.
// ---------------------------------------------------------------------------
template <int KRES, int CXM, int NPT, int TARGET, int TMAX>
__global__ __launch_bounds__(256) void k_thresh(int* __restrict__ thr) {
  __shared__ int cnt;
  int q = blockIdx.x, tid = threadIdx.x;
  int qx = q & 31, qy = q >> 5;
  int cx = qx * CXM, cy = qy * CXM;
  int d[NPT];
#pragma unroll
  for (int j = 0; j < NPT; ++j) {
    int k = tid * NPT + j;
    int kx = k & (KRES - 1), ky = k / KRES;
    int dx = cx - kx, dy = cy - ky;
    d[j] = dx * dx + dy * dy;
  }
  int lo = 0, hi = TMAX;
  while (lo < hi) {  // lo/hi uniform across block
    int mid = (lo + hi) >> 1;
    if (tid == 0) cnt = 0;
    __syncthreads();
    int c = 0;
#pragma unroll
    for (int j = 0; j < NPT; ++j) c += (d[j] <= mid) ? 1 : 0;
    atomicAdd(&cnt, c);
    __syncthreads();
    int total = cnt;
    __syncthreads();
    if (total >= TARGET) hi = mid; else lo = mid + 1;
  }
  if (tid == 0) thr[q] = lo;
}

// ---------------------------------------------------------------------------
// Generic 256x256 GEMM: out = epi(A[M,256] * B + bias [+ addend])
// BL=0: B[k][n] = W[n*256+k]  (lin: w is [out,in] row-major, contract over in)
// BL=1: B[k][n] = W[(n>>5)*8192 + k*32 + (n&31)]  (per-head value weights)
// OL=0: out[m*256+n]; OL=1: heads layout out[((b*8+h)*N + r)*32 + v], N=1<<NS
// ---------------------------------------------------------------------------
template <int BL, int OL, bool GEL, bool ADD>
__global__ __launch_bounds__(256) void k_gemm(const float* __restrict__ A,
                                              const float* __restrict__ W,
                                              const float* __restrict__ bias,
                                              const float* __restrict__ addend,
                                              float* __restrict__ out, int NS) {
  __shared__ float As[16][68];  // [k][m], padded for float4 align + banks
  __shared__ float Bs[16][68];  // [k][n]
  int tid = threadIdx.x;
  int m0 = blockIdx.x * 64, n0 = blockIdx.y * 64;
  int lr = tid >> 2, lk = (tid & 3) << 2;
  int ty = tid >> 4, tx = tid & 15;
  float acc[4][4] = {};
  for (int kk = 0; kk < 256; kk += 16) {
    float4 av = *(const float4*)(A + (size_t)(m0 + lr) * 256 + kk + lk);
    As[lk + 0][lr] = av.x; As[lk + 1][lr] = av.y;
    As[lk + 2][lr] = av.z; As[lk + 3][lr] = av.w;
    if (BL == 0) {
      float4 wv = *(const float4*)(W + (size_t)(n0 + lr) * 256 + kk + lk);
      Bs[lk + 0][lr] = wv.x; Bs[lk + 1][lr] = wv.y;
      Bs[lk + 2][lr] = wv.z; Bs[lk + 3][lr] = wv.w;
    } else {
      int k = tid >> 4, nl = (tid & 15) << 2;
      int ng = n0 + nl;
      float4 wv = *(const float4*)(W + (size_t)(ng >> 5) * 8192 +
                                   (size_t)(kk + k) * 32 + (ng & 31));
      *(float4*)&Bs[k][nl] = wv;
    }
    __syncthreads();
#pragma unroll
    for (int k = 0; k < 16; ++k) {
      float4 a = *(const float4*)&As[k][ty * 4];
      float4 bv = *(const float4*)&Bs[k][tx * 4];
      float ar[4] = {a.x, a.y, a.z, a.w};
      float br[4] = {bv.x, bv.y, bv.z, bv.w};
#pragma unroll
      for (int i = 0; i < 4; ++i)
#pragma unroll
        for (int j = 0; j < 4; ++j) acc[i][j] += ar[i] * br[j];
    }
    __syncthreads();
  }
#pragma unroll
  for (int i = 0; i < 4; ++i) {
    int m = m0 + ty * 4 + i;
#pragma unroll
    for (int j = 0; j < 4; ++j) {
      int n = n0 + tx * 4 + j;
      float c = acc[i][j];
      if (bias) c += bias[n];
      if (ADD) c += addend[(size_t)m * 256 + n];
      if (GEL) c = gelu_f(c);
      if (OL == 0) {
        out[(size_t)m * 256 + n] = c;
      } else {
        int N = 1 << NS;
        int bb = m >> NS, rrow = m & (N - 1);
        out[(((size_t)(bb * 8 + (n >> 5))) * N + rrow) * 32 + (n & 31)] = c;
      }
    }
  }
}

// ---------------------------------------------------------------------------
// Sparse (disc-masked) attention for down/proc. One block per (q,b).
// thread = h*32+v. Scans the bounding box of {d_int <= T}; branch is
// block-uniform. denom accumulated redundantly per thread (cheap exp).
// ---------------------------------------------------------------------------
template <int KRES, int CXM, int DSHIFT>
__global__ __launch_bounds__(256) void k_att_sparse(
    const float* __restrict__ value,  // [B,8,KRES*KRES,32]
    const float* __restrict__ rvec, const int* __restrict__ thr,
    float* __restrict__ out /* [B,1024,256] */) {
  int q = blockIdx.x, b = blockIdx.y;
  int tid = threadIdx.x, h = tid >> 5, v = tid & 31;
  float sc = head_scale(rvec[h]) * (1.0f / (float)(1 << DSHIFT));
  int qx = q & 31, qy = q >> 5;
  int cx = qx * CXM, cy = qy * CXM;
  int T = thr[q];
  int rad = (int)sqrtf((float)T);
  while ((rad + 1) * (rad + 1) <= T) ++rad;  // guard approx sqrt
  int x0 = max(0, cx - rad), x1 = min(KRES - 1, cx + rad);
  int y0 = max(0, cy - rad), y1 = min(KRES - 1, cy + rad);
  const float* vb = value + (((size_t)b * 8 + h) * (KRES * KRES)) * 32 + v;
  float acc = 0.f, den = 0.f;
  for (int ky = y0; ky <= y1; ++ky) {
    int dy = cy - ky;
    int dy2 = dy * dy;
    for (int kx = x0; kx <= x1; ++kx) {
      int dx = cx - kx;
      int d = dx * dx + dy2;
      if (d <= T) {  // uniform across block
        float w = expf(-sc * (float)d);
        den += w;
        acc += w * vb[(size_t)(ky * KRES + kx) * 32];
      }
    }
  }
  out[((size_t)b * 1024 + q) * 256 + tid] = gelu_f(acc / den);
}

// ---------------------------------------------------------------------------
// Dense up-attention as GEMM with on-the-fly A = exp(-(d-dmin)*sc).
// Block: 64 q-rows x 32 v for one (b,h). Fused softmax denominator.
// ---------------------------------------------------------------------------
__global__ __launch_bounds__(256) void k_att_up(
    const float* __restrict__ value,  // [B,8,1024,32]
    const float* __restrict__ rvec, float* __restrict__ out /* [B,4096,256] */) {
  __shared__ float As[16][68];   // [k][q]
  __shared__ float Bs[16][34];   // [k][v]
  __shared__ float dpart[256];
  int tid = threadIdx.x;
  int q0 = blockIdx.x * 64, h = blockIdx.y, b = blockIdx.z;
  float sc = head_scale(rvec[h]) * (1.0f / 8192.0f);
  int qr_g = tid >> 2;  // generation row
  int qg = q0 + qr_g;
  int qx = qg & 63, qy = qg >> 6;
  int dmin = (qx & 1) + (qy & 1);  // row min of d_int (max-subtraction)
  int ks0 = (tid & 3) * 4;
  int ty = tid >> 4, tx = tid & 15;
  const float* vb = value + ((size_t)(b * 8 + h) * 1024) * 32;
  float acc[4][2] = {};
  float myden = 0.f;
  for (int kk = 0; kk < 1024; kk += 16) {
#pragma unroll
    for (int j = 0; j < 4; ++j) {
      int k = kk + ks0 + j;
      int kx = k & 31, ky = k >> 5;
      int dx = qx - 2 * kx, dy = qy - 2 * ky;
      int d = dx * dx + dy * dy - dmin;
      float w = expf(-sc * (float)d);
      As[ks0 + j][qr_g] = w;
      myden += w;
    }
    {
      int k = tid >> 4, vv = (tid & 15) * 2;
      int idx = (kk + k) * 32 + vv;
      Bs[k][vv] = vb[idx];
      Bs[k][vv + 1] = vb[idx + 1];
    }
    __syncthreads();
#pragma unroll
    for (int k = 0; k < 16; ++k) {
      float4 a = *(const float4*)&As[k][ty * 4];
      float b0 = Bs[k][tx * 2], b1 = Bs[k][tx * 2 + 1];
      acc[0][0] += a.x * b0; acc[0][1] += a.x * b1;
      acc[1][0] += a.y * b0; acc[1][1] += a.y * b1;
      acc[2][0] += a.z * b0; acc[2][1] += a.z * b1;
      acc[3][0] += a.w * b0; acc[3][1] += a.w * b1;
    }
    __syncthreads();
  }
  dpart[tid] = myden;
  __syncthreads();
#pragma unroll
  for (int i = 0; i < 4; ++i) {
    int r = ty * 4 + i;
    float den = dpart[r * 4] + dpart[r * 4 + 1] + dpart[r * 4 + 2] + dpart[r * 4 + 3];
    float inv = 1.0f / den;
#pragma unroll
    for (int j = 0; j < 2; ++j) {
      float o = gelu_f(acc[i][j] * inv);
      out[((size_t)b * 4096 + q0 + r) * 256 + h * 32 + tx * 2 + j] = o;
    }
  }
}

// ---------------------------------------------------------------------------
// Decoder fc2: out[row] = dot(h[row,:], w[0,:]) + b[0]. One wave per row.
// ---------------------------------------------------------------------------
__global__ __launch_bounds__(256) void k_fc2(const float* __restrict__ h,
                                             const float* __restrict__ w,
                                             const float* __restrict__ b,
                                             float* __restrict__ out) {
  int row = blockIdx.x * 4 + (threadIdx.x >> 6);
  int lane = threadIdx.x & 63;
  float4 hv = *(const float4*)(h + (size_t)row * 256 + lane * 4);
  float4 wv = *(const float4*)(w + lane * 4);
  float s = hv.x * wv.x + hv.y * wv.y + hv.z * wv.z + hv.w * wv.w;
#pragma unroll
  for (int off = 32; off > 0; off >>= 1) s += __shfl_down(s, off, 64);
  if (lane == 0) out[row] = s + b[0];
}

// ---------------------------------------------------------------------------
extern "C" void kernel_launch(void* const* d_in, const int* in_sizes, int n_in,
                              void* d_out, int out_size, void* d_ws,
                              size_t ws_size, hipStream_t stream) {
  const float* x      = (const float*)d_in[0];
  const float* en_w   = (const float*)d_in[1];
  const float* en_b   = (const float*)d_in[2];
  const float* down_r = (const float*)d_in[3];
  const float* down_w = (const float*)d_in[4];
  const float* pa_r   = (const float*)d_in[5];
  const float* pa_w   = (const float*)d_in[6];
  const float* mlp1_w = (const float*)d_in[7];
  const float* mlp1_b = (const float*)d_in[8];
  const float* mlp2_w = (const float*)d_in[9];
  const float* mlp2_b = (const float*)d_in[10];
  const float* res_w  = (const float*)d_in[11];
  const float* res_b  = (const float*)d_in[12];
  const float* up_r   = (const float*)d_in[13];
  const float* up_w   = (const float*)d_in[14];
  const float* de1_w  = (const float*)d_in[15];
  const float* de1_b  = (const float*)d_in[16];
  const float* de2_w  = (const float*)d_in[17];
  const float* de2_b  = (const float*)d_in[18];
  float* out = (float*)d_out;

  float* ws = (float*)d_ws;
  float* A = ws;                  // [8,4096,256] enc out; later up-att out
  float* B = A + 8388608;         // [8,8,4096,32] value_down; later dec hidden
  float* lat0 = B + 8388608;      // four [8,1024,256] latent buffers
  float* lat1 = lat0 + 2097152;
  float* lat2 = lat1 + 2097152;
  float* lat3 = lat2 + 2097152;
  int* thrD = (int*)(lat3 + 2097152);  // [1024]
  int* thrP = thrD + 1024;             // [1024]
  float* lat[4] = {lat0, lat1, lat2, lat3};

  // 1. encoder -> A
  k_enc<<<32768, 256, 0, stream>>>(x, en_w, en_b, A);
  // 2. thresholds (input-independent, but recomputed each launch; ~us)
  k_thresh<64, 2, 16, 82, 7938><<<1024, 256, 0, stream>>>(thrD);
  k_thresh<32, 1, 4, 103, 1922><<<1024, 256, 0, stream>>>(thrP);
  // 3. down: value (heads layout) then sparse attention -> lat0
  k_gemm<1, 1, false, false><<<dim3(512, 4), 256, 0, stream>>>(
      A, down_w, nullptr, nullptr, B, 12);
  k_att_sparse<64, 2, 13><<<dim3(1024, 8), 256, 0, stream>>>(B, down_r, thrD, lat0);
  // 4. processor blocks
  int cur = 0;
  for (int i = 0; i < 4; ++i) {
    int vbuf = (cur + 1) & 3, pbuf = (cur + 2) & 3, tbuf = (cur + 3) & 3;
    k_gemm<1, 1, false, false><<<dim3(128, 4), 256, 0, stream>>>(
        lat[cur], pa_w + (size_t)i * 65536, nullptr, nullptr, lat[vbuf], 10);
    k_att_sparse<32, 1, 11><<<dim3(1024, 8), 256, 0, stream>>>(
        lat[vbuf], pa_r + i * 8, thrP, lat[pbuf]);
    k_gemm<0, 0, true, false><<<dim3(128, 4), 256, 0, stream>>>(
        lat[pbuf], mlp1_w + (size_t)i * 65536, mlp1_b + i * 256, nullptr,
        lat[tbuf], 0);
    k_gemm<0, 0, false, false><<<dim3(128, 4), 256, 0, stream>>>(
        lat[tbuf], mlp2_w + (size_t)i * 65536, mlp2_b + i * 256, nullptr,
        lat[vbuf], 0);
    k_gemm<0, 0, true, true><<<dim3(128, 4), 256, 0, stream>>>(
        lat[cur], res_w + (size_t)i * 65536, res_b + i * 256, lat[vbuf],
        lat[pbuf], 0);
    cur = pbuf;
  }
  // 5. up: value then dense attention (fused denom) -> A
  int vbuf = (cur + 1) & 3;
  k_gemm<1, 1, false, false><<<dim3(128, 4), 256, 0, stream>>>(
      lat[cur], up_w, nullptr, nullptr, lat[vbuf], 10);
  k_att_up<<<dim3(64, 8, 8), 256, 0, stream>>>(lat[vbuf], up_r, A);
  // 6. decoder
  k_gemm<0, 0, true, false><<<dim3(512, 4), 256, 0, stream>>>(
      A, de1_w, de1_b, nullptr, B, 0);
  k_fc2<<<8192, 256, 0, stream>>>(B, de2_w, de2_b, out);
}

// Round 2
// 1274.869 us; speedup vs baseline: 1.3848x; 1.3848x over previous
//
#include <hip/hip_runtime.h>
#include <math.h>

// ---------------------------------------------------------------------------
// PiTWithCoords: position-attention transformer on fixed grids.
//  * m_dist EXACT in fp32: d_int / 2^S (down S=13, proc S=11, up S=13).
//  * percentile mask == integer threshold on d_int (order statistic).
//  * att weights are input- AND batch-independent -> precompute normalized
//    weights once per launch (k_klist), batch all 8 b per block.
// All compute fp32 (no fp32 MFMA on CDNA4; bf16 would blow the 1.24e-4 abs
// threshold). Fast-path transcendentals via __expf (v_exp_f32).
// ---------------------------------------------------------------------------

#define PI_F 3.14159265358979323846f

__device__ __forceinline__ float gelu_f(float x) {
  // tanh-form gelu; tanh(u) = 1 - 2/(exp(2u)+1)  (safe at +/-inf)
  float u = 0.7978845608028654f * (x + 0.044715f * x * x * x);
  float e = __expf(2.0f * u);
  float t = 1.0f - 2.0f / (e + 1.0f);
  return 0.5f * x * (1.0f + t);
}

__device__ __forceinline__ float head_scale(float r) {
  return tanf(0.25f * PI_F * (1.0f - 1e-7f) * (1.0f + sinf(r)));
}

// ---------------------------------------------------------------------------
// Encoder: out[row,o] = gelu(sum_i x[row,i]*W[o,i] + b[o])
// ---------------------------------------------------------------------------
__global__ __launch_bounds__(256) void k_enc(const float* __restrict__ x,
                                             const float* __restrict__ w,
                                             const float* __restrict__ b,
                                             float* __restrict__ out) {
  int row = blockIdx.x;
  int o = threadIdx.x;
  float4 xv = *(const float4*)(x + (size_t)row * 4);
  float4 wv = *(const float4*)(w + (size_t)o * 4);
  float s = xv.x * wv.x + xv.y * wv.y + xv.z * wv.z + xv.w * wv.w + b[o];
  out[(size_t)row * 256 + o] = gelu_f(s);
}

// ---------------------------------------------------------------------------
// Order-statistic integer threshold per query row (binary search count).
// ---------------------------------------------------------------------------
template <int KRES, int CXM, int NPT, int TARGET, int TMAX>
__global__ __launch_bounds__(256) void k_thresh(int* __restrict__ thr) {
  __shared__ int cnt;
  int q = blockIdx.x, tid = threadIdx.x;
  int qx = q & 31, qy = q >> 5;
  int cx = qx * CXM, cy = qy * CXM;
  int d[NPT];
#pragma unroll
  for (int j = 0; j < NPT; ++j) {
    int k = tid * NPT + j;
    int kx = k & (KRES - 1), ky = k / KRES;
    int dx = cx - kx, dy = cy - ky;
    d[j] = dx * dx + dy * dy;
  }
  int lo = 0, hi = TMAX;
  while (lo < hi) {
    int mid = (lo + hi) >> 1;
    if (tid == 0) cnt = 0;
    __syncthreads();
    int c = 0;
#pragma unroll
    for (int j = 0; j < NPT; ++j) c += (d[j] <= mid) ? 1 : 0;
    atomicAdd(&cnt, c);
    __syncthreads();
    int total = cnt;
    __syncthreads();
    if (total >= TARGET) hi = mid; else lo = mid + 1;
  }
  if (tid == 0) thr[q] = lo;
}

// ---------------------------------------------------------------------------
// Precompute per-q compacted key list + per-(h,q,j) softmax-normalized
// weights. One block per q. Input-independent -> tiny (1024 blocks).
// ---------------------------------------------------------------------------
template <int KRES, int CXM, int DSHIFT, int JMAX>
__global__ __launch_bounds__(256) void k_klist(
    const float* __restrict__ rvec, const int* __restrict__ thr,
    int* __restrict__ klist, int* __restrict__ kcnt,
    float* __restrict__ wlist) {
  __shared__ int cntS;
  __shared__ int sidx[JMAX];
  __shared__ int sdv[JMAX];
  __shared__ float wbuf[8][JMAX];
  __shared__ float denS[8];
  int q = blockIdx.x, tid = threadIdx.x;
  int qx = q & 31, qy = q >> 5;
  int cx = qx * CXM, cy = qy * CXM;
  int T = thr[q];
  if (tid == 0) cntS = 0;
  __syncthreads();
  int rad = (int)sqrtf((float)T);
  while ((rad + 1) * (rad + 1) <= T) ++rad;
  while (rad > 0 && rad * rad > T) --rad;
  int x0 = max(0, cx - rad), x1 = min(KRES - 1, cx + rad);
  int y0 = max(0, cy - rad), y1 = min(KRES - 1, cy + rad);
  int W = x1 - x0 + 1, H = y1 - y0 + 1, tot = W * H;
  for (int p = tid; p < tot; p += 256) {
    int kx = x0 + p % W, ky = y0 + p / W;
    int dx = cx - kx, dy = cy - ky;
    int d = dx * dx + dy * dy;
    if (d <= T) {
      int s = atomicAdd(&cntS, 1);
      if (s < JMAX) { sidx[s] = ky * KRES + kx; sdv[s] = d; }
    }
  }
  __syncthreads();
  int cnt = min(cntS, JMAX);
  int h = tid >> 5, j0 = tid & 31;
  float sc = head_scale(rvec[h]) * (1.0f / (float)(1 << DSHIFT));
  float ds = 0.f;
  for (int j = j0; j < cnt; j += 32) {
    float w = __expf(-sc * (float)sdv[j]);
    wbuf[h][j] = w;
    ds += w;
  }
#pragma unroll
  for (int off = 16; off > 0; off >>= 1) ds += __shfl_down(ds, off, 32);
  if (j0 == 0) denS[h] = ds;
  __syncthreads();
  float inv = 1.0f / denS[h];
  for (int j = j0; j < cnt; j += 32)
    wlist[((size_t)h * 1024 + q) * JMAX + j] = wbuf[h][j] * inv;
  if (tid == 0) kcnt[q] = cnt;
  if (h == 0)
    for (int j = j0; j < cnt; j += 32) klist[(size_t)q * JMAX + j] = sidx[j];
}

// ---------------------------------------------------------------------------
// Generic 256x256 GEMM: out = epi(A[M,256] * B + bias [+ addend])
// BL=0: B[k][n] = W[n*256+k];  BL=1: per-head value W[(n>>5)*8192+k*32+(n&31)]
// OL=0: out[m*256+n];  OL=1: value layout out[((h*N + r)*8 + b)*32 + v],
//       h=n>>5, v=n&31, b=m>>NS, r=m&(N-1), N=1<<NS.
// ---------------------------------------------------------------------------
template <int BL, int OL, bool GEL, bool ADD>
__global__ __launch_bounds__(256) void k_gemm(const float* __restrict__ A,
                                              const float* __restrict__ W,
                                              const float* __restrict__ bias,
                                              const float* __restrict__ addend,
                                              float* __restrict__ out, int NS) {
  __shared__ float As[16][68];
  __shared__ float Bs[16][68];
  int tid = threadIdx.x;
  int m0 = blockIdx.x * 64, n0 = blockIdx.y * 64;
  int lr = tid >> 2, lk = (tid & 3) << 2;
  int ty = tid >> 4, tx = tid & 15;
  float acc[4][4] = {};
  for (int kk = 0; kk < 256; kk += 16) {
    float4 av = *(const float4*)(A + (size_t)(m0 + lr) * 256 + kk + lk);
    As[lk + 0][lr] = av.x; As[lk + 1][lr] = av.y;
    As[lk + 2][lr] = av.z; As[lk + 3][lr] = av.w;
    if (BL == 0) {
      float4 wv = *(const float4*)(W + (size_t)(n0 + lr) * 256 + kk + lk);
      Bs[lk + 0][lr] = wv.x; Bs[lk + 1][lr] = wv.y;
      Bs[lk + 2][lr] = wv.z; Bs[lk + 3][lr] = wv.w;
    } else {
      int k = tid >> 4, nl = (tid & 15) << 2;
      int ng = n0 + nl;
      float4 wv = *(const float4*)(W + (size_t)(ng >> 5) * 8192 +
                                   (size_t)(kk + k) * 32 + (ng & 31));
      *(float4*)&Bs[k][nl] = wv;
    }
    __syncthreads();
#pragma unroll
    for (int k = 0; k < 16; ++k) {
      float4 a = *(const float4*)&As[k][ty * 4];
      float4 bv = *(const float4*)&Bs[k][tx * 4];
      float ar[4] = {a.x, a.y, a.z, a.w};
      float br[4] = {bv.x, bv.y, bv.z, bv.w};
#pragma unroll
      for (int i = 0; i < 4; ++i)
#pragma unroll
        for (int j = 0; j < 4; ++j) acc[i][j] += ar[i] * br[j];
    }
    __syncthreads();
  }
#pragma unroll
  for (int i = 0; i < 4; ++i) {
    int m = m0 + ty * 4 + i;
#pragma unroll
    for (int j = 0; j < 4; ++j) {
      int n = n0 + tx * 4 + j;
      float c = acc[i][j];
      if (bias) c += bias[n];
      if (ADD) c += addend[(size_t)m * 256 + n];
      if (GEL) c = gelu_f(c);
      if (OL == 0) {
        out[(size_t)m * 256 + n] = c;
      } else {
        int N = 1 << NS;
        int bb = m >> NS, r = m & (N - 1);
        out[(((size_t)(n >> 5) * N + r) * 8 + bb) * 32 + (n & 31)] = c;
      }
    }
  }
}

// ---------------------------------------------------------------------------
// Sparse attention, all batches per block. One block per q; thread=(h,v);
// acc[8] over b. Pure gather-FMA: weights precomputed & normalized.
// value layout [h][NK][b*32+v].
// ---------------------------------------------------------------------------
template <int NK, int JMAX>
__global__ __launch_bounds__(256) void k_att2(
    const float* __restrict__ value, const int* __restrict__ klist,
    const int* __restrict__ kcnt, const float* __restrict__ wlist,
    float* __restrict__ out /* [8,1024,256] */) {
  __shared__ int kls[JMAX];
  __shared__ float wls[8][JMAX];
  int q = blockIdx.x, tid = threadIdx.x;
  int cnt = kcnt[q];
  for (int i = tid; i < cnt; i += 256) kls[i] = klist[(size_t)q * JMAX + i];
  for (int i = tid; i < 8 * JMAX; i += 256) {
    int hh = i / JMAX, j = i - hh * JMAX;
    if (j < cnt) wls[hh][j] = wlist[((size_t)hh * 1024 + q) * JMAX + j];
  }
  __syncthreads();
  int h = tid >> 5, v = tid & 31;
  const float* vb = value + (size_t)h * NK * 256 + v;
  float acc[8] = {};
  for (int j = 0; j < cnt; ++j) {
    float w = wls[h][j];
    const float* vp = vb + (size_t)kls[j] * 256;
#pragma unroll
    for (int b = 0; b < 8; ++b) acc[b] += w * vp[b * 32];
  }
#pragma unroll
  for (int b = 0; b < 8; ++b)
    out[((size_t)b * 1024 + q) * 256 + tid] = gelu_f(acc[b]);
}

// ---------------------------------------------------------------------------
// Dense up-attention: block = (64 q) x (all 256 (b,v) cols) for one head.
// A(exp weights) generated on the fly (batch-shared), fused denominator.
// 8x8 micro-tile: 64 FMA per 4 LDS b128 reads.
// ---------------------------------------------------------------------------
__global__ __launch_bounds__(256) void k_att_up2(
    const float* __restrict__ value,  // [h][1024][b*32+v]
    const float* __restrict__ rvec,
    float* __restrict__ out /* [8,4096,256] */) {
  __shared__ float As[16][72];
  __shared__ float Bs[16][260];
  __shared__ float dpart[256];
  __shared__ float rden[64];
  int tid = threadIdx.x;
  int q0 = blockIdx.x * 64, h = blockIdx.y;
  float sc = head_scale(rvec[h]) * (1.0f / 8192.0f);
  int qr = tid >> 2, ks0 = (tid & 3) * 4;
  int qg = q0 + qr, qx = qg & 63, qy = qg >> 6;
  int dmin = (qx & 1) + (qy & 1);  // row-min of d_int (softmax max-shift)
  int ty = tid >> 5, tx = tid & 31;
  const float* vb = value + (size_t)h * 1024 * 256;
  int bk = tid >> 4, bc = (tid & 15) * 16;
  float acc[8][8] = {};
  float dsum = 0.f;
  for (int kk = 0; kk < 1024; kk += 16) {
    const float* src = vb + (size_t)(kk + bk) * 256 + bc;
    float4 b0 = *(const float4*)(src);
    float4 b1 = *(const float4*)(src + 4);
    float4 b2 = *(const float4*)(src + 8);
    float4 b3 = *(const float4*)(src + 12);
    *(float4*)&Bs[bk][bc] = b0;
    *(float4*)&Bs[bk][bc + 4] = b1;
    *(float4*)&Bs[bk][bc + 8] = b2;
    *(float4*)&Bs[bk][bc + 12] = b3;
#pragma unroll
    for (int j = 0; j < 4; ++j) {
      int k = kk + ks0 + j;
      int kx = k & 31, ky = k >> 5;
      int dx = qx - 2 * kx, dy = qy - 2 * ky;
      int d = dx * dx + dy * dy - dmin;
      float w = __expf(-sc * (float)d);
      As[ks0 + j][qr] = w;
      dsum += w;
    }
    __syncthreads();
#pragma unroll
    for (int k = 0; k < 16; ++k) {
      float a[8], bb[8];
      *(float4*)&a[0] = *(const float4*)&As[k][ty * 8];
      *(float4*)&a[4] = *(const float4*)&As[k][ty * 8 + 4];
      *(float4*)&bb[0] = *(const float4*)&Bs[k][tx * 8];
      *(float4*)&bb[4] = *(const float4*)&Bs[k][tx * 8 + 4];
#pragma unroll
      for (int i = 0; i < 8; ++i)
#pragma unroll
        for (int j2 = 0; j2 < 8; ++j2) acc[i][j2] += a[i] * bb[j2];
    }
    __syncthreads();
  }
  dpart[tid] = dsum;
  __syncthreads();
  if (tid < 64)
    rden[tid] = 1.0f / (dpart[tid * 4] + dpart[tid * 4 + 1] +
                        dpart[tid * 4 + 2] + dpart[tid * 4 + 3]);
  __syncthreads();
  int b = (tx * 8) >> 5, v0 = (tx * 8) & 31;
#pragma unroll
  for (int i = 0; i < 8; ++i) {
    int r = ty * 8 + i;
    float inv = rden[r];
#pragma unroll
    for (int j2 = 0; j2 < 8; ++j2)
      out[((size_t)b * 4096 + q0 + r) * 256 + h * 32 + v0 + j2] =
          gelu_f(acc[i][j2] * inv);
  }
}

// ---------------------------------------------------------------------------
// Decoder fc2: out[row] = dot(h[row,:], w) + b. One wave per row.
// ---------------------------------------------------------------------------
__global__ __launch_bounds__(256) void k_fc2(const float* __restrict__ h,
                                             const float* __restrict__ w,
                                             const float* __restrict__ b,
                                             float* __restrict__ out) {
  int row = blockIdx.x * 4 + (threadIdx.x >> 6);
  int lane = threadIdx.x & 63;
  float4 hv = *(const float4*)(h + (size_t)row * 256 + lane * 4);
  float4 wv = *(const float4*)(w + lane * 4);
  float s = hv.x * wv.x + hv.y * wv.y + hv.z * wv.z + hv.w * wv.w;
#pragma unroll
  for (int off = 32; off > 0; off >>= 1) s += __shfl_down(s, off, 64);
  if (lane == 0) out[row] = s + b[0];
}

// ---------------------------------------------------------------------------
extern "C" void kernel_launch(void* const* d_in, const int* in_sizes, int n_in,
                              void* d_out, int out_size, void* d_ws,
                              size_t ws_size, hipStream_t stream) {
  const float* x      = (const float*)d_in[0];
  const float* en_w   = (const float*)d_in[1];
  const float* en_b   = (const float*)d_in[2];
  const float* down_r = (const float*)d_in[3];
  const float* down_w = (const float*)d_in[4];
  const float* pa_r   = (const float*)d_in[5];
  const float* pa_w   = (const float*)d_in[6];
  const float* mlp1_w = (const float*)d_in[7];
  const float* mlp1_b = (const float*)d_in[8];
  const float* mlp2_w = (const float*)d_in[9];
  const float* mlp2_b = (const float*)d_in[10];
  const float* res_w  = (const float*)d_in[11];
  const float* res_b  = (const float*)d_in[12];
  const float* up_r   = (const float*)d_in[13];
  const float* up_w   = (const float*)d_in[14];
  const float* de1_w  = (const float*)d_in[15];
  const float* de1_b  = (const float*)d_in[16];
  const float* de2_w  = (const float*)d_in[17];
  const float* de2_b  = (const float*)d_in[18];
  float* out = (float*)d_out;

  constexpr int JMAX = 144;
  float* ws = (float*)d_ws;
  float* A = ws;                  // [8,4096,256] enc out; later up-att out
  float* B = A + 8388608;         // [h,4096,256] value_down; later dec hidden
  float* lat0 = B + 8388608;      // four [8,1024,256] latent buffers
  float* lat1 = lat0 + 2097152;
  float* lat2 = lat1 + 2097152;
  float* lat3 = lat2 + 2097152;
  float* wlD = lat3 + 2097152;    // [8,1024,JMAX]
  float* wlP = wlD + 8 * 1024 * JMAX;
  int* thrD = (int*)(wlP + 8 * 1024 * JMAX);
  int* thrP = thrD + 1024;
  int* cntD = thrP + 1024;
  int* cntP = cntD + 1024;
  int* klD = cntP + 1024;         // [1024,JMAX]
  int* klP = klD + 1024 * JMAX;
  float* lat[4] = {lat0, lat1, lat2, lat3};

  // 1. encoder
  k_enc<<<32768, 256, 0, stream>>>(x, en_w, en_b, A);
  // 2. thresholds + key lists + normalized weights (input-independent, ~us)
  k_thresh<64, 2, 16, 82, 7938><<<1024, 256, 0, stream>>>(thrD);
  k_thresh<32, 1, 4, 103, 1922><<<1024, 256, 0, stream>>>(thrP);
  k_klist<64, 2, 13, JMAX><<<1024, 256, 0, stream>>>(down_r, thrD, klD, cntD, wlD);
  k_klist<32, 1, 11, JMAX><<<1024, 256, 0, stream>>>(pa_r, thrP, klP, cntP, wlP);
  // 3. down: value ([h][4096][bv]) then batched sparse attention
  k_gemm<1, 1, false, false><<<dim3(512, 4), 256, 0, stream>>>(
      A, down_w, nullptr, nullptr, B, 12);
  k_att2<4096, JMAX><<<1024, 256, 0, stream>>>(B, klD, cntD, wlD, lat0);
  // 4. processor blocks
  int cur = 0;
  for (int i = 0; i < 4; ++i) {
    int vbuf = (cur + 1) & 3, pbuf = (cur + 2) & 3, tbuf = (cur + 3) & 3;
    k_gemm<1, 1, false, false><<<dim3(128, 4), 256, 0, stream>>>(
        lat[cur], pa_w + (size_t)i * 65536, nullptr, nullptr, lat[vbuf], 10);
    k_att2<1024, JMAX><<<1024, 256, 0, stream>>>(lat[vbuf], klP, cntP, wlP,
                                                 lat[pbuf]);
    k_gemm<0, 0, true, false><<<dim3(128, 4), 256, 0, stream>>>(
        lat[pbuf], mlp1_w + (size_t)i * 65536, mlp1_b + i * 256, nullptr,
        lat[tbuf], 0);
    k_gemm<0, 0, false, false><<<dim3(128, 4), 256, 0, stream>>>(
        lat[tbuf], mlp2_w + (size_t)i * 65536, mlp2_b + i * 256, nullptr,
        lat[vbuf], 0);
    k_gemm<0, 0, true, true><<<dim3(128, 4), 256, 0, stream>>>(
        lat[cur], res_w + (size_t)i * 65536, res_b + i * 256, lat[vbuf],
        lat[pbuf], 0);
    cur = pbuf;
  }
  // 5. up: value ([h][1024][bv]) then dense batched attention
  int vbuf = (cur + 1) & 3;
  k_gemm<1, 1, false, false><<<dim3(128, 4), 256, 0, stream>>>(
      lat[cur], up_w, nullptr, nullptr, lat[vbuf], 10);
  k_att_up2<<<dim3(64, 8), 256, 0, stream>>>(lat[vbuf], up_r, A);
  // 6. decoder
  k_gemm<0, 0, true, false><<<dim3(512, 4), 256, 0, stream>>>(
      A, de1_w, de1_b, nullptr, B, 0);
  k_fc2<<<8192, 256, 0, stream>>>(B, de2_w, de2_b, out);
}

// Round 3
// 1168.651 us; speedup vs baseline: 1.5107x; 1.0909x over previous
//
#include <hip/hip_runtime.h>
#include <math.h>

// ---------------------------------------------------------------------------
// PiTWithCoords: position-attention transformer on fixed grids.
//  * m_dist EXACT in fp32: d_int / 2^S (down S=13, proc S=11, up S=13).
//  * percentile mask == integer threshold on d_int (order statistic).
//  * att weights are input- AND batch-independent -> precompute normalized
//    weights once per launch (k_klist), batch all 8 b per block.
// All compute fp32 (no fp32 MFMA on CDNA4). __expf fast paths.
// R2: k_att_up3 = conflict-free Bs mapping (contiguous float4 per lane),
//     col-split x2 for occupancy; mlp2+res fused into one K=512 GEMM.
// ---------------------------------------------------------------------------

#define PI_F 3.14159265358979323846f

__device__ __forceinline__ float gelu_f(float x) {
  float u = 0.7978845608028654f * (x + 0.044715f * x * x * x);
  float e = __expf(2.0f * u);
  float t = 1.0f - 2.0f / (e + 1.0f);
  return 0.5f * x * (1.0f + t);
}

__device__ __forceinline__ float head_scale(float r) {
  return tanf(0.25f * PI_F * (1.0f - 1e-7f) * (1.0f + sinf(r)));
}

// ---------------------------------------------------------------------------
__global__ __launch_bounds__(256) void k_enc(const float* __restrict__ x,
                                             const float* __restrict__ w,
                                             const float* __restrict__ b,
                                             float* __restrict__ out) {
  int row = blockIdx.x;
  int o = threadIdx.x;
  float4 xv = *(const float4*)(x + (size_t)row * 4);
  float4 wv = *(const float4*)(w + (size_t)o * 4);
  float s = xv.x * wv.x + xv.y * wv.y + xv.z * wv.z + xv.w * wv.w + b[o];
  out[(size_t)row * 256 + o] = gelu_f(s);
}

// ---------------------------------------------------------------------------
template <int KRES, int CXM, int NPT, int TARGET, int TMAX>
__global__ __launch_bounds__(256) void k_thresh(int* __restrict__ thr) {
  __shared__ int cnt;
  int q = blockIdx.x, tid = threadIdx.x;
  int qx = q & 31, qy = q >> 5;
  int cx = qx * CXM, cy = qy * CXM;
  int d[NPT];
#pragma unroll
  for (int j = 0; j < NPT; ++j) {
    int k = tid * NPT + j;
    int kx = k & (KRES - 1), ky = k / KRES;
    int dx = cx - kx, dy = cy - ky;
    d[j] = dx * dx + dy * dy;
  }
  int lo = 0, hi = TMAX;
  while (lo < hi) {
    int mid = (lo + hi) >> 1;
    if (tid == 0) cnt = 0;
    __syncthreads();
    int c = 0;
#pragma unroll
    for (int j = 0; j < NPT; ++j) c += (d[j] <= mid) ? 1 : 0;
    atomicAdd(&cnt, c);
    __syncthreads();
    int total = cnt;
    __syncthreads();
    if (total >= TARGET) hi = mid; else lo = mid + 1;
  }
  if (tid == 0) thr[q] = lo;
}

// ---------------------------------------------------------------------------
template <int KRES, int CXM, int DSHIFT, int JMAX>
__global__ __launch_bounds__(256) void k_klist(
    const float* __restrict__ rvec, const int* __restrict__ thr,
    int* __restrict__ klist, int* __restrict__ kcnt,
    float* __restrict__ wlist) {
  __shared__ int cntS;
  __shared__ int sidx[JMAX];
  __shared__ int sdv[JMAX];
  __shared__ float wbuf[8][JMAX];
  __shared__ float denS[8];
  int q = blockIdx.x, tid = threadIdx.x;
  int qx = q & 31, qy = q >> 5;
  int cx = qx * CXM, cy = qy * CXM;
  int T = thr[q];
  if (tid == 0) cntS = 0;
  __syncthreads();
  int rad = (int)sqrtf((float)T);
  while ((rad + 1) * (rad + 1) <= T) ++rad;
  while (rad > 0 && rad * rad > T) --rad;
  int x0 = max(0, cx - rad), x1 = min(KRES - 1, cx + rad);
  int y0 = max(0, cy - rad), y1 = min(KRES - 1, cy + rad);
  int W = x1 - x0 + 1, H = y1 - y0 + 1, tot = W * H;
  for (int p = tid; p < tot; p += 256) {
    int kx = x0 + p % W, ky = y0 + p / W;
    int dx = cx - kx, dy = cy - ky;
    int d = dx * dx + dy * dy;
    if (d <= T) {
      int s = atomicAdd(&cntS, 1);
      if (s < JMAX) { sidx[s] = ky * KRES + kx; sdv[s] = d; }
    }
  }
  __syncthreads();
  int cnt = min(cntS, JMAX);
  int h = tid >> 5, j0 = tid & 31;
  float sc = head_scale(rvec[h]) * (1.0f / (float)(1 << DSHIFT));
  float ds = 0.f;
  for (int j = j0; j < cnt; j += 32) {
    float w = __expf(-sc * (float)sdv[j]);
    wbuf[h][j] = w;
    ds += w;
  }
#pragma unroll
  for (int off = 16; off > 0; off >>= 1) ds += __shfl_down(ds, off, 32);
  if (j0 == 0) denS[h] = ds;
  __syncthreads();
  float inv = 1.0f / denS[h];
  for (int j = j0; j < cnt; j += 32)
    wlist[((size_t)h * 1024 + q) * JMAX + j] = wbuf[h][j] * inv;
  if (tid == 0) kcnt[q] = cnt;
  if (h == 0)
    for (int j = j0; j < cnt; j += 32) klist[(size_t)q * JMAX + j] = sidx[j];
}

// ---------------------------------------------------------------------------
// Generic 256x256 GEMM (as R1).
// ---------------------------------------------------------------------------
template <int BL, int OL, bool GEL, bool ADD>
__global__ __launch_bounds__(256) void k_gemm(const float* __restrict__ A,
                                              const float* __restrict__ W,
                                              const float* __restrict__ bias,
                                              const float* __restrict__ addend,
                                              float* __restrict__ out, int NS) {
  __shared__ float As[16][68];
  __shared__ float Bs[16][68];
  int tid = threadIdx.x;
  int m0 = blockIdx.x * 64, n0 = blockIdx.y * 64;
  int lr = tid >> 2, lk = (tid & 3) << 2;
  int ty = tid >> 4, tx = tid & 15;
  float acc[4][4] = {};
  for (int kk = 0; kk < 256; kk += 16) {
    float4 av = *(const float4*)(A + (size_t)(m0 + lr) * 256 + kk + lk);
    As[lk + 0][lr] = av.x; As[lk + 1][lr] = av.y;
    As[lk + 2][lr] = av.z; As[lk + 3][lr] = av.w;
    if (BL == 0) {
      float4 wv = *(const float4*)(W + (size_t)(n0 + lr) * 256 + kk + lk);
      Bs[lk + 0][lr] = wv.x; Bs[lk + 1][lr] = wv.y;
      Bs[lk + 2][lr] = wv.z; Bs[lk + 3][lr] = wv.w;
    } else {
      int k = tid >> 4, nl = (tid & 15) << 2;
      int ng = n0 + nl;
      float4 wv = *(const float4*)(W + (size_t)(ng >> 5) * 8192 +
                                   (size_t)(kk + k) * 32 + (ng & 31));
      *(float4*)&Bs[k][nl] = wv;
    }
    __syncthreads();
#pragma unroll
    for (int k = 0; k < 16; ++k) {
      float4 a = *(const float4*)&As[k][ty * 4];
      float4 bv = *(const float4*)&Bs[k][tx * 4];
      float ar[4] = {a.x, a.y, a.z, a.w};
      float br[4] = {bv.x, bv.y, bv.z, bv.w};
#pragma unroll
      for (int i = 0; i < 4; ++i)
#pragma unroll
        for (int j = 0; j < 4; ++j) acc[i][j] += ar[i] * br[j];
    }
    __syncthreads();
  }
#pragma unroll
  for (int i = 0; i < 4; ++i) {
    int m = m0 + ty * 4 + i;
#pragma unroll
    for (int j = 0; j < 4; ++j) {
      int n = n0 + tx * 4 + j;
      float c = acc[i][j];
      if (bias) c += bias[n];
      if (ADD) c += addend[(size_t)m * 256 + n];
      if (GEL) c = gelu_f(c);
      if (OL == 0) {
        out[(size_t)m * 256 + n] = c;
      } else {
        int N = 1 << NS;
        int bb = m >> NS, r = m & (N - 1);
        out[(((size_t)(n >> 5) * N + r) * 8 + bb) * 32 + (n & 31)] = c;
      }
    }
  }
}

// ---------------------------------------------------------------------------
// Fused dual-A GEMM: out = gelu(A1*W1^T + A2*W2^T + b1 + b2). K=512 virtual.
// ---------------------------------------------------------------------------
__global__ __launch_bounds__(256) void k_gemm_dual(
    const float* __restrict__ A1, const float* __restrict__ W1,
    const float* __restrict__ A2, const float* __restrict__ W2,
    const float* __restrict__ b1, const float* __restrict__ b2,
    float* __restrict__ out) {
  __shared__ float As[16][68];
  __shared__ float Bs[16][68];
  int tid = threadIdx.x;
  int m0 = blockIdx.x * 64, n0 = blockIdx.y * 64;
  int lr = tid >> 2, lk = (tid & 3) << 2;
  int ty = tid >> 4, tx = tid & 15;
  float acc[4][4] = {};
  for (int kk = 0; kk < 512; kk += 16) {
    const float* A = (kk < 256) ? A1 : A2;
    const float* W = (kk < 256) ? W1 : W2;
    int kb = kk & 255;
    float4 av = *(const float4*)(A + (size_t)(m0 + lr) * 256 + kb + lk);
    As[lk + 0][lr] = av.x; As[lk + 1][lr] = av.y;
    As[lk + 2][lr] = av.z; As[lk + 3][lr] = av.w;
    float4 wv = *(const float4*)(W + (size_t)(n0 + lr) * 256 + kb + lk);
    Bs[lk + 0][lr] = wv.x; Bs[lk + 1][lr] = wv.y;
    Bs[lk + 2][lr] = wv.z; Bs[lk + 3][lr] = wv.w;
    __syncthreads();
#pragma unroll
    for (int k = 0; k < 16; ++k) {
      float4 a = *(const float4*)&As[k][ty * 4];
      float4 bv = *(const float4*)&Bs[k][tx * 4];
      float ar[4] = {a.x, a.y, a.z, a.w};
      float br[4] = {bv.x, bv.y, bv.z, bv.w};
#pragma unroll
      for (int i = 0; i < 4; ++i)
#pragma unroll
        for (int j = 0; j < 4; ++j) acc[i][j] += ar[i] * br[j];
    }
    __syncthreads();
  }
#pragma unroll
  for (int i = 0; i < 4; ++i) {
    int m = m0 + ty * 4 + i;
#pragma unroll
    for (int j = 0; j < 4; ++j) {
      int n = n0 + tx * 4 + j;
      out[(size_t)m * 256 + n] = gelu_f(acc[i][j] + b1[n] + b2[n]);
    }
  }
}

// ---------------------------------------------------------------------------
// Sparse attention, all batches per block (as R1).
// ---------------------------------------------------------------------------
template <int NK, int JMAX>
__global__ __launch_bounds__(256) void k_att2(
    const float* __restrict__ value, const int* __restrict__ klist,
    const int* __restrict__ kcnt, const float* __restrict__ wlist,
    float* __restrict__ out /* [8,1024,256] */) {
  __shared__ int kls[JMAX];
  __shared__ float wls[8][JMAX];
  int q = blockIdx.x, tid = threadIdx.x;
  int cnt = kcnt[q];
  for (int i = tid; i < cnt; i += 256) kls[i] = klist[(size_t)q * JMAX + i];
  for (int i = tid; i < 8 * JMAX; i += 256) {
    int hh = i / JMAX, j = i - hh * JMAX;
    if (j < cnt) wls[hh][j] = wlist[((size_t)hh * 1024 + q) * JMAX + j];
  }
  __syncthreads();
  int h = tid >> 5, v = tid & 31;
  const float* vb = value + (size_t)h * NK * 256 + v;
  float acc[8] = {};
  for (int j = 0; j < cnt; ++j) {
    float w = wls[h][j];
    const float* vp = vb + (size_t)kls[j] * 256;
#pragma unroll
    for (int b = 0; b < 8; ++b) acc[b] += w * vp[b * 32];
  }
#pragma unroll
  for (int b = 0; b < 8; ++b)
    out[((size_t)b * 1024 + q) * 256 + tid] = gelu_f(acc[b]);
}

// ---------------------------------------------------------------------------
// Dense up-attention v3: block = 64 q x 128 (b,v) cols, one head.
// grid (64, 8, 2). Micro-tile 8q x 4 contiguous cols -> conflict-free Bs
// (consecutive lanes read consecutive float4), As reads are wave-broadcast.
// ---------------------------------------------------------------------------
__global__ __launch_bounds__(256) void k_att_up3(
    const float* __restrict__ value,  // [h][1024][bv=256]
    const float* __restrict__ rvec,
    float* __restrict__ out /* [8,4096,256] */) {
  __shared__ float As[16][76];   // padded: 76*4 % 16 == 0 (b128-aligned)
  __shared__ float Bs[16][132];
  __shared__ float dpart[256];
  __shared__ float rden[64];
  int tid = threadIdx.x;
  int q0 = blockIdx.x * 64, h = blockIdx.y, c0 = blockIdx.z * 128;
  float sc = head_scale(rvec[h]) * (1.0f / 8192.0f);
  int qr = tid >> 2, ks0 = (tid & 3) * 4;   // exp-gen mapping
  int qg = q0 + qr, qx = qg & 63, qy = qg >> 6;
  int dmin = (qx & 1) + (qy & 1);
  int ty = tid >> 5, tx = tid & 31;          // micro-tile mapping
  int bk = tid >> 4, bc = (tid & 15) * 8;    // Bs staging mapping
  const float* vb = value + (size_t)h * 1024 * 256 + c0;
  float acc[8][4] = {};
  float dsum = 0.f;
  for (int kk = 0; kk < 1024; kk += 16) {
    const float* src = vb + (size_t)(kk + bk) * 256 + bc;
    float4 s0 = *(const float4*)(src);
    float4 s1 = *(const float4*)(src + 4);
    *(float4*)&Bs[bk][bc] = s0;
    *(float4*)&Bs[bk][bc + 4] = s1;
#pragma unroll
    for (int j = 0; j < 4; ++j) {
      int k = kk + ks0 + j;
      int kx = k & 31, ky = k >> 5;
      int dx = qx - 2 * kx, dy = qy - 2 * ky;
      int d = dx * dx + dy * dy - dmin;
      float w = __expf(-sc * (float)d);
      As[ks0 + j][qr] = w;
      dsum += w;
    }
    __syncthreads();
#pragma unroll
    for (int k = 0; k < 16; ++k) {
      float a[8], bb[4];
      *(float4*)&a[0] = *(const float4*)&As[k][ty * 8];      // broadcast
      *(float4*)&a[4] = *(const float4*)&As[k][ty * 8 + 4];  // broadcast
      *(float4*)&bb[0] = *(const float4*)&Bs[k][tx * 4];     // conflict-free
#pragma unroll
      for (int i = 0; i < 8; ++i)
#pragma unroll
        for (int j2 = 0; j2 < 4; ++j2) acc[i][j2] += a[i] * bb[j2];
    }
    __syncthreads();
  }
  dpart[tid] = dsum;
  __syncthreads();
  if (tid < 64)
    rden[tid] = 1.0f / (dpart[tid * 4] + dpart[tid * 4 + 1] +
                        dpart[tid * 4 + 2] + dpart[tid * 4 + 3]);
  __syncthreads();
  int g = c0 + tx * 4;          // global (b,v) col of this thread's float4
  int b = g >> 5, v = g & 31;   // v multiple of 4 -> aligned float4 store
#pragma unroll
  for (int i = 0; i < 8; ++i) {
    int r = ty * 8 + i;
    float inv = rden[r];
    float4 o;
    o.x = gelu_f(acc[i][0] * inv);
    o.y = gelu_f(acc[i][1] * inv);
    o.z = gelu_f(acc[i][2] * inv);
    o.w = gelu_f(acc[i][3] * inv);
    *(float4*)&out[((size_t)b * 4096 + q0 + r) * 256 + h * 32 + v] = o;
  }
}

// ---------------------------------------------------------------------------
__global__ __launch_bounds__(256) void k_fc2(const float* __restrict__ h,
                                             const float* __restrict__ w,
                                             const float* __restrict__ b,
                                             float* __restrict__ out) {
  int row = blockIdx.x * 4 + (threadIdx.x >> 6);
  int lane = threadIdx.x & 63;
  float4 hv = *(const float4*)(h + (size_t)row * 256 + lane * 4);
  float4 wv = *(const float4*)(w + lane * 4);
  float s = hv.x * wv.x + hv.y * wv.y + hv.z * wv.z + hv.w * wv.w;
#pragma unroll
  for (int off = 32; off > 0; off >>= 1) s += __shfl_down(s, off, 64);
  if (lane == 0) out[row] = s + b[0];
}

// ---------------------------------------------------------------------------
extern "C" void kernel_launch(void* const* d_in, const int* in_sizes, int n_in,
                              void* d_out, int out_size, void* d_ws,
                              size_t ws_size, hipStream_t stream) {
  const float* x      = (const float*)d_in[0];
  const float* en_w   = (const float*)d_in[1];
  const float* en_b   = (const float*)d_in[2];
  const float* down_r = (const float*)d_in[3];
  const float* down_w = (const float*)d_in[4];
  const float* pa_r   = (const float*)d_in[5];
  const float* pa_w   = (const float*)d_in[6];
  const float* mlp1_w = (const float*)d_in[7];
  const float* mlp1_b = (const float*)d_in[8];
  const float* mlp2_w = (const float*)d_in[9];
  const float* mlp2_b = (const float*)d_in[10];
  const float* res_w  = (const float*)d_in[11];
  const float* res_b  = (const float*)d_in[12];
  const float* up_r   = (const float*)d_in[13];
  const float* up_w   = (const float*)d_in[14];
  const float* de1_w  = (const float*)d_in[15];
  const float* de1_b  = (const float*)d_in[16];
  const float* de2_w  = (const float*)d_in[17];
  const float* de2_b  = (const float*)d_in[18];
  float* out = (float*)d_out;

  constexpr int JMAX = 144;
  float* ws = (float*)d_ws;
  float* A = ws;                  // [8,4096,256] enc out; later up-att out
  float* B = A + 8388608;         // [h,4096,256] value_down; later dec hidden
  float* lat0 = B + 8388608;
  float* lat1 = lat0 + 2097152;
  float* lat2 = lat1 + 2097152;
  float* lat3 = lat2 + 2097152;
  float* wlD = lat3 + 2097152;    // [8,1024,JMAX]
  float* wlP = wlD + 8 * 1024 * JMAX;
  int* thrD = (int*)(wlP + 8 * 1024 * JMAX);
  int* thrP = thrD + 1024;
  int* cntD = thrP + 1024;
  int* cntP = cntD + 1024;
  int* klD = cntP + 1024;         // [1024,JMAX]
  int* klP = klD + 1024 * JMAX;
  float* lat[4] = {lat0, lat1, lat2, lat3};

  // 1. encoder
  k_enc<<<32768, 256, 0, stream>>>(x, en_w, en_b, A);
  // 2. thresholds + key lists + normalized weights (input-independent)
  k_thresh<64, 2, 16, 82, 7938><<<1024, 256, 0, stream>>>(thrD);
  k_thresh<32, 1, 4, 103, 1922><<<1024, 256, 0, stream>>>(thrP);
  k_klist<64, 2, 13, JMAX><<<1024, 256, 0, stream>>>(down_r, thrD, klD, cntD, wlD);
  k_klist<32, 1, 11, JMAX><<<1024, 256, 0, stream>>>(pa_r, thrP, klP, cntP, wlP);
  // 3. down: value ([h][4096][bv]) then batched sparse attention
  k_gemm<1, 1, false, false><<<dim3(512, 4), 256, 0, stream>>>(
      A, down_w, nullptr, nullptr, B, 12);
  k_att2<4096, JMAX><<<1024, 256, 0, stream>>>(B, klD, cntD, wlD, lat0);
  // 4. processor blocks (mlp2+res fused)
  int cur = 0;
  for (int i = 0; i < 4; ++i) {
    int vbuf = (cur + 1) & 3, pbuf = (cur + 2) & 3, tbuf = (cur + 3) & 3;
    k_gemm<1, 1, false, false><<<dim3(128, 4), 256, 0, stream>>>(
        lat[cur], pa_w + (size_t)i * 65536, nullptr, nullptr, lat[vbuf], 10);
    k_att2<1024, JMAX><<<1024, 256, 0, stream>>>(lat[vbuf], klP, cntP, wlP,
                                                 lat[pbuf]);
    k_gemm<0, 0, true, false><<<dim3(128, 4), 256, 0, stream>>>(
        lat[pbuf], mlp1_w + (size_t)i * 65536, mlp1_b + i * 256, nullptr,
        lat[tbuf], 0);
    k_gemm_dual<<<dim3(128, 4), 256, 0, stream>>>(
        lat[tbuf], mlp2_w + (size_t)i * 65536, lat[cur],
        res_w + (size_t)i * 65536, mlp2_b + i * 256, res_b + i * 256,
        lat[pbuf]);
    cur = pbuf;
  }
  // 5. up: value ([h][1024][bv]) then dense batched attention
  int vbuf = (cur + 1) & 3;
  k_gemm<1, 1, false, false><<<dim3(128, 4), 256, 0, stream>>>(
      lat[cur], up_w, nullptr, nullptr, lat[vbuf], 10);
  k_att_up3<<<dim3(64, 8, 2), 256, 0, stream>>>(lat[vbuf], up_r, A);
  // 6. decoder
  k_gemm<0, 0, true, false><<<dim3(512, 4), 256, 0, stream>>>(
      A, de1_w, de1_b, nullptr, B, 0);
  k_fc2<<<8192, 256, 0, stream>>>(B, de2_w, de2_b, out);
}

// Round 4
// 1020.820 us; speedup vs baseline: 1.7295x; 1.1448x over previous
//
#include <hip/hip_runtime.h>
#include <math.h>

// ---------------------------------------------------------------------------
// PiTWithCoords: position-attention transformer on fixed grids.
//  * m_dist EXACT in fp32: d_int / 2^S (down S=13, proc S=11, up S=13).
//  * percentile mask == integer threshold on d_int (order statistic).
//  * att weights input- AND batch-independent; down/proc = sparse gather
//    with precomputed normalized weights.
//  * UP attention (locality 200 => unmasked) is SEPARABLE:
//    exp(-sc*((qx-2kx)^2+(qy-2ky)^2)) = Ax[qx,kx]*Ay[qy,ky]  (Kronecker),
//    so O = Ay*(Ax*V) and den = Sx[qx]*Sy[qy]. 21x FLOP reduction.
// All compute fp32 (no fp32 MFMA on CDNA4). __expf fast paths.
// ---------------------------------------------------------------------------

#define PI_F 3.14159265358979323846f

__device__ __forceinline__ float gelu_f(float x) {
  float u = 0.7978845608028654f * (x + 0.044715f * x * x * x);
  float e = __expf(2.0f * u);
  float t = 1.0f - 2.0f / (e + 1.0f);
  return 0.5f * x * (1.0f + t);
}

__device__ __forceinline__ float head_scale(float r) {
  return tanf(0.25f * PI_F * (1.0f - 1e-7f) * (1.0f + sinf(r)));
}

// ---------------------------------------------------------------------------
__global__ __launch_bounds__(256) void k_enc(const float* __restrict__ x,
                                             const float* __restrict__ w,
                                             const float* __restrict__ b,
                                             float* __restrict__ out) {
  int row = blockIdx.x;
  int o = threadIdx.x;
  float4 xv = *(const float4*)(x + (size_t)row * 4);
  float4 wv = *(const float4*)(w + (size_t)o * 4);
  float s = xv.x * wv.x + xv.y * wv.y + xv.z * wv.z + xv.w * wv.w + b[o];
  out[(size_t)row * 256 + o] = gelu_f(s);
}

// ---------------------------------------------------------------------------
template <int KRES, int CXM, int NPT, int TARGET, int TMAX>
__global__ __launch_bounds__(256) void k_thresh(int* __restrict__ thr) {
  __shared__ int cnt;
  int q = blockIdx.x, tid = threadIdx.x;
  int qx = q & 31, qy = q >> 5;
  int cx = qx * CXM, cy = qy * CXM;
  int d[NPT];
#pragma unroll
  for (int j = 0; j < NPT; ++j) {
    int k = tid * NPT + j;
    int kx = k & (KRES - 1), ky = k / KRES;
    int dx = cx - kx, dy = cy - ky;
    d[j] = dx * dx + dy * dy;
  }
  int lo = 0, hi = TMAX;
  while (lo < hi) {
    int mid = (lo + hi) >> 1;
    if (tid == 0) cnt = 0;
    __syncthreads();
    int c = 0;
#pragma unroll
    for (int j = 0; j < NPT; ++j) c += (d[j] <= mid) ? 1 : 0;
    atomicAdd(&cnt, c);
    __syncthreads();
    int total = cnt;
    __syncthreads();
    if (total >= TARGET) hi = mid; else lo = mid + 1;
  }
  if (tid == 0) thr[q] = lo;
}

// ---------------------------------------------------------------------------
template <int KRES, int CXM, int DSHIFT, int JMAX>
__global__ __launch_bounds__(256) void k_klist(
    const float* __restrict__ rvec, const int* __restrict__ thr,
    int* __restrict__ klist, int* __restrict__ kcnt,
    float* __restrict__ wlist) {
  __shared__ int cntS;
  __shared__ int sidx[JMAX];
  __shared__ int sdv[JMAX];
  __shared__ float wbuf[8][JMAX];
  __shared__ float denS[8];
  int q = blockIdx.x, tid = threadIdx.x;
  int qx = q & 31, qy = q >> 5;
  int cx = qx * CXM, cy = qy * CXM;
  int T = thr[q];
  if (tid == 0) cntS = 0;
  __syncthreads();
  int rad = (int)sqrtf((float)T);
  while ((rad + 1) * (rad + 1) <= T) ++rad;
  while (rad > 0 && rad * rad > T) --rad;
  int x0 = max(0, cx - rad), x1 = min(KRES - 1, cx + rad);
  int y0 = max(0, cy - rad), y1 = min(KRES - 1, cy + rad);
  int W = x1 - x0 + 1, H = y1 - y0 + 1, tot = W * H;
  for (int p = tid; p < tot; p += 256) {
    int kx = x0 + p % W, ky = y0 + p / W;
    int dx = cx - kx, dy = cy - ky;
    int d = dx * dx + dy * dy;
    if (d <= T) {
      int s = atomicAdd(&cntS, 1);
      if (s < JMAX) { sidx[s] = ky * KRES + kx; sdv[s] = d; }
    }
  }
  __syncthreads();
  int cnt = min(cntS, JMAX);
  int h = tid >> 5, j0 = tid & 31;
  float sc = head_scale(rvec[h]) * (1.0f / (float)(1 << DSHIFT));
  float ds = 0.f;
  for (int j = j0; j < cnt; j += 32) {
    float w = __expf(-sc * (float)sdv[j]);
    wbuf[h][j] = w;
    ds += w;
  }
#pragma unroll
  for (int off = 16; off > 0; off >>= 1) ds += __shfl_down(ds, off, 32);
  if (j0 == 0) denS[h] = ds;
  __syncthreads();
  float inv = 1.0f / denS[h];
  for (int j = j0; j < cnt; j += 32)
    wlist[((size_t)h * 1024 + q) * JMAX + j] = wbuf[h][j] * inv;
  if (tid == 0) kcnt[q] = cnt;
  if (h == 0)
    for (int j = j0; j < cnt; j += 32) klist[(size_t)q * JMAX + j] = sidx[j];
}

// ---------------------------------------------------------------------------
// Generic 256-K GEMM, BK=32 (half the barriers of BK=16).
// BL=0: B[k][n]=W[n*256+k]; BL=1: per-head value W[(n>>5)*8192+k*32+(n&31)]
// OL=0: out[m*256+n]; OL=1: out[(((n>>5)*N + r)*8 + b)*32 + (n&31)], N=1<<NS
// ADD: += addend[m*256+n]; bias/bias2 nullable.
// ---------------------------------------------------------------------------
template <int BL, int OL, bool GEL, bool ADD>
__global__ __launch_bounds__(256) void k_gemm(const float* __restrict__ A,
                                              const float* __restrict__ W,
                                              const float* __restrict__ bias,
                                              const float* __restrict__ bias2,
                                              const float* __restrict__ addend,
                                              float* __restrict__ out, int NS) {
  __shared__ float As[32][68];
  __shared__ float Bs[32][68];
  int tid = threadIdx.x;
  int m0 = blockIdx.x * 64, n0 = blockIdx.y * 64;
  int lr = tid >> 2, lk = (tid & 3) << 2;
  int ty = tid >> 4, tx = tid & 15;
  float acc[4][4] = {};
  for (int kk = 0; kk < 256; kk += 32) {
#pragma unroll
    for (int half = 0; half < 2; ++half) {
      int k4 = lk + half * 16;
      float4 av = *(const float4*)(A + (size_t)(m0 + lr) * 256 + kk + k4);
      As[k4 + 0][lr] = av.x; As[k4 + 1][lr] = av.y;
      As[k4 + 2][lr] = av.z; As[k4 + 3][lr] = av.w;
      if (BL == 0) {
        float4 wv = *(const float4*)(W + (size_t)(n0 + lr) * 256 + kk + k4);
        Bs[k4 + 0][lr] = wv.x; Bs[k4 + 1][lr] = wv.y;
        Bs[k4 + 2][lr] = wv.z; Bs[k4 + 3][lr] = wv.w;
      } else {
        int k = (tid >> 4) + half * 16, nl = (tid & 15) << 2;
        int ng = n0 + nl;
        float4 wv = *(const float4*)(W + (size_t)(ng >> 5) * 8192 +
                                     (size_t)(kk + k) * 32 + (ng & 31));
        *(float4*)&Bs[k][nl] = wv;
      }
    }
    __syncthreads();
#pragma unroll
    for (int k = 0; k < 32; ++k) {
      float4 a = *(const float4*)&As[k][ty * 4];
      float4 bv = *(const float4*)&Bs[k][tx * 4];
      float ar[4] = {a.x, a.y, a.z, a.w};
      float br[4] = {bv.x, bv.y, bv.z, bv.w};
#pragma unroll
      for (int i = 0; i < 4; ++i)
#pragma unroll
        for (int j = 0; j < 4; ++j) acc[i][j] += ar[i] * br[j];
    }
    __syncthreads();
  }
#pragma unroll
  for (int i = 0; i < 4; ++i) {
    int m = m0 + ty * 4 + i;
#pragma unroll
    for (int j = 0; j < 4; ++j) {
      int n = n0 + tx * 4 + j;
      float c = acc[i][j];
      if (bias) c += bias[n];
      if (bias2) c += bias2[n];
      if (ADD) c += addend[(size_t)m * 256 + n];
      if (GEL) c = gelu_f(c);
      if (OL == 0) {
        out[(size_t)m * 256 + n] = c;
      } else {
        int N = 1 << NS;
        int bb = m >> NS, r = m & (N - 1);
        out[(((size_t)(n >> 5) * N + r) * 8 + bb) * 32 + (n & 31)] = c;
      }
    }
  }
}

// ---------------------------------------------------------------------------
// Merged pa-value + residual GEMM: one dispatch, grid (128, 8).
// y<4: value = A*pa_w (BL=1 layout, OL=1 store, N=1024)
// y>=4: res_pre = A*res_w^T (BL=0, OL=0 store, no bias — added later)
// ---------------------------------------------------------------------------
__global__ __launch_bounds__(256) void k_value_res(
    const float* __restrict__ A, const float* __restrict__ Wv,
    const float* __restrict__ Wr, float* __restrict__ value,
    float* __restrict__ res_pre) {
  __shared__ float As[32][68];
  __shared__ float Bs[32][68];
  int tid = threadIdx.x;
  bool isv = blockIdx.y < 4;
  int m0 = blockIdx.x * 64;
  int n0 = (isv ? blockIdx.y : blockIdx.y - 4) * 64;
  int lr = tid >> 2, lk = (tid & 3) << 2;
  int ty = tid >> 4, tx = tid & 15;
  float acc[4][4] = {};
  for (int kk = 0; kk < 256; kk += 32) {
#pragma unroll
    for (int half = 0; half < 2; ++half) {
      int k4 = lk + half * 16;
      float4 av = *(const float4*)(A + (size_t)(m0 + lr) * 256 + kk + k4);
      As[k4 + 0][lr] = av.x; As[k4 + 1][lr] = av.y;
      As[k4 + 2][lr] = av.z; As[k4 + 3][lr] = av.w;
      if (isv) {
        int k = (tid >> 4) + half * 16, nl = (tid & 15) << 2;
        int ng = n0 + nl;
        float4 wv = *(const float4*)(Wv + (size_t)(ng >> 5) * 8192 +
                                     (size_t)(kk + k) * 32 + (ng & 31));
        *(float4*)&Bs[k][nl] = wv;
      } else {
        float4 wv = *(const float4*)(Wr + (size_t)(n0 + lr) * 256 + kk + k4);
        Bs[k4 + 0][lr] = wv.x; Bs[k4 + 1][lr] = wv.y;
        Bs[k4 + 2][lr] = wv.z; Bs[k4 + 3][lr] = wv.w;
      }
    }
    __syncthreads();
#pragma unroll
    for (int k = 0; k < 32; ++k) {
      float4 a = *(const float4*)&As[k][ty * 4];
      float4 bv = *(const float4*)&Bs[k][tx * 4];
      float ar[4] = {a.x, a.y, a.z, a.w};
      float br[4] = {bv.x, bv.y, bv.z, bv.w};
#pragma unroll
      for (int i = 0; i < 4; ++i)
#pragma unroll
        for (int j = 0; j < 4; ++j) acc[i][j] += ar[i] * br[j];
    }
    __syncthreads();
  }
#pragma unroll
  for (int i = 0; i < 4; ++i) {
    int m = m0 + ty * 4 + i;
#pragma unroll
    for (int j = 0; j < 4; ++j) {
      int n = n0 + tx * 4 + j;
      float c = acc[i][j];
      if (isv) {
        int bb = m >> 10, r = m & 1023;
        value[(((size_t)(n >> 5) * 1024 + r) * 8 + bb) * 32 + (n & 31)] = c;
      } else {
        res_pre[(size_t)m * 256 + n] = c;
      }
    }
  }
}

// ---------------------------------------------------------------------------
// Sparse attention, all batches per block.
// ---------------------------------------------------------------------------
template <int NK, int JMAX>
__global__ __launch_bounds__(256) void k_att2(
    const float* __restrict__ value, const int* __restrict__ klist,
    const int* __restrict__ kcnt, const float* __restrict__ wlist,
    float* __restrict__ out /* [8,1024,256] */) {
  __shared__ int kls[JMAX];
  __shared__ float wls[8][JMAX];
  int q = blockIdx.x, tid = threadIdx.x;
  int cnt = kcnt[q];
  for (int i = tid; i < cnt; i += 256) kls[i] = klist[(size_t)q * JMAX + i];
  for (int i = tid; i < 8 * JMAX; i += 256) {
    int hh = i / JMAX, j = i - hh * JMAX;
    if (j < cnt) wls[hh][j] = wlist[((size_t)hh * 1024 + q) * JMAX + j];
  }
  __syncthreads();
  int h = tid >> 5, v = tid & 31;
  const float* vb = value + (size_t)h * NK * 256 + v;
  float acc[8] = {};
  for (int j = 0; j < cnt; ++j) {
    float w = wls[h][j];
    const float* vp = vb + (size_t)kls[j] * 256;
#pragma unroll
    for (int b = 0; b < 8; ++b) acc[b] += w * vp[b * 32];
  }
#pragma unroll
  for (int b = 0; b < 8; ++b)
    out[((size_t)b * 1024 + q) * 256 + tid] = gelu_f(acc[b]);
}

// ---------------------------------------------------------------------------
// Separable up-attention, stage 1: T[h][qx][ky][bv] = sum_kx Ax[qx][kx]*V.
// Block = (ky, h); thread = bv. V row cached in 32 VGPRs.
// Ax row-shifted by dxmin=(qx&1): shift cancels in normalization.
// ---------------------------------------------------------------------------
__global__ __launch_bounds__(256) void k_up_s1(
    const float* __restrict__ value,  // [h][1024][bv]
    const float* __restrict__ rvec, float* __restrict__ T) {
  __shared__ float AxL[64][33];
  int ky = blockIdx.x, h = blockIdx.y, tid = threadIdx.x;
  float sc = head_scale(rvec[h]) * (1.0f / 8192.0f);
  float v[32];
  const float* vb = value + ((size_t)h * 1024 + ky * 32) * 256 + tid;
#pragma unroll
  for (int kx = 0; kx < 32; ++kx) v[kx] = vb[kx * 256];
  if (tid < 64) {
    int qx = tid, dxmin = qx & 1;
    for (int kx = 0; kx < 32; ++kx) {
      int dx = qx - 2 * kx;
      AxL[qx][kx] = __expf(-sc * (float)(dx * dx - dxmin));
    }
  }
  __syncthreads();
  float* tb = T + (((size_t)h * 64) * 32 + ky) * 256 + tid;
  for (int qx = 0; qx < 64; ++qx) {
    float acc = 0.f;
#pragma unroll
    for (int kx = 0; kx < 32; ++kx) acc += AxL[qx][kx] * v[kx];
    tb[(size_t)qx * 32 * 256] = acc;
  }
}

// ---------------------------------------------------------------------------
// Separable up-attention, stage 2: O[b][qy*64+qx][h*32+v] =
//   gelu( (sum_ky Ay[qy][ky]*T[h][qx][ky][bv]) / (Sx[qx]*Sy[qy]) ).
// Block = (qx, h); thread = bv.
// ---------------------------------------------------------------------------
__global__ __launch_bounds__(256) void k_up_s2(
    const float* __restrict__ T, const float* __restrict__ rvec,
    float* __restrict__ out /* [8,4096,256] */) {
  __shared__ float AyL[64][33];
  __shared__ float Sy[64];
  __shared__ float SxS;
  int qx = blockIdx.x, h = blockIdx.y, tid = threadIdx.x;
  float sc = head_scale(rvec[h]) * (1.0f / 8192.0f);
  float t[32];
  const float* tb = T + ((size_t)h * 64 + qx) * 32 * 256 + tid;
#pragma unroll
  for (int ky = 0; ky < 32; ++ky) t[ky] = tb[ky * 256];
  if (tid < 64) {
    int qy = tid, dymin = qy & 1;
    float s = 0.f;
    for (int ky = 0; ky < 32; ++ky) {
      int dy = qy - 2 * ky;
      float e = __expf(-sc * (float)(dy * dy - dymin));
      AyL[qy][ky] = e;
      s += e;
    }
    Sy[qy] = s;
  } else if (tid >= 64 && tid < 96) {
    int kx = tid - 64, dxmin = qx & 1;
    int dx = qx - 2 * kx;
    float e = __expf(-sc * (float)(dx * dx - dxmin));
#pragma unroll
    for (int off = 16; off > 0; off >>= 1) e += __shfl_down(e, off, 32);
    if (kx == 0) SxS = e;
  }
  __syncthreads();
  float invSx = 1.0f / SxS;
  int b = tid >> 5, v = tid & 31;
  float* ob = out + ((size_t)b * 4096 + qx) * 256 + h * 32 + v;
  for (int qy = 0; qy < 64; ++qy) {
    float acc = 0.f;
#pragma unroll
    for (int ky = 0; ky < 32; ++ky) acc += AyL[qy][ky] * t[ky];
    float o = gelu_f(acc * invSx / Sy[qy]);
    ob[(size_t)qy * 64 * 256] = o;
  }
}

// ---------------------------------------------------------------------------
__global__ __launch_bounds__(256) void k_fc2(const float* __restrict__ h,
                                             const float* __restrict__ w,
                                             const float* __restrict__ b,
                                             float* __restrict__ out) {
  int row = blockIdx.x * 4 + (threadIdx.x >> 6);
  int lane = threadIdx.x & 63;
  float4 hv = *(const float4*)(h + (size_t)row * 256 + lane * 4);
  float4 wv = *(const float4*)(w + lane * 4);
  float s = hv.x * wv.x + hv.y * wv.y + hv.z * wv.z + hv.w * wv.w;
#pragma unroll
  for (int off = 32; off > 0; off >>= 1) s += __shfl_down(s, off, 64);
  if (lane == 0) out[row] = s + b[0];
}

// ---------------------------------------------------------------------------
extern "C" void kernel_launch(void* const* d_in, const int* in_sizes, int n_in,
                              void* d_out, int out_size, void* d_ws,
                              size_t ws_size, hipStream_t stream) {
  const float* x      = (const float*)d_in[0];
  const float* en_w   = (const float*)d_in[1];
  const float* en_b   = (const float*)d_in[2];
  const float* down_r = (const float*)d_in[3];
  const float* down_w = (const float*)d_in[4];
  const float* pa_r   = (const float*)d_in[5];
  const float* pa_w   = (const float*)d_in[6];
  const float* mlp1_w = (const float*)d_in[7];
  const float* mlp1_b = (const float*)d_in[8];
  const float* mlp2_w = (const float*)d_in[9];
  const float* mlp2_b = (const float*)d_in[10];
  const float* res_w  = (const float*)d_in[11];
  const float* res_b  = (const float*)d_in[12];
  const float* up_r   = (const float*)d_in[13];
  const float* up_w   = (const float*)d_in[14];
  const float* de1_w  = (const float*)d_in[15];
  const float* de1_b  = (const float*)d_in[16];
  const float* de2_w  = (const float*)d_in[17];
  const float* de2_b  = (const float*)d_in[18];
  float* out = (float*)d_out;

  constexpr int JMAX = 144;
  float* ws = (float*)d_ws;
  float* A = ws;                  // [8,4096,256] enc out; later up-att out
  float* B = A + 8388608;         // [h][4096][bv] value_down; T; dec hidden
  float* lat0 = B + 8388608;      // h in/out of processor iters
  float* lat1 = lat0 + 2097152;   // value / mlp1-out
  float* lat2 = lat1 + 2097152;   // res_pre
  float* lat3 = lat2 + 2097152;   // pa_out
  float* wlD = lat3 + 2097152;    // [8,1024,JMAX]
  float* wlP = wlD + 8 * 1024 * JMAX;
  int* thrD = (int*)(wlP + 8 * 1024 * JMAX);
  int* thrP = thrD + 1024;
  int* cntD = thrP + 1024;
  int* cntP = cntD + 1024;
  int* klD = cntP + 1024;         // [1024,JMAX]
  int* klP = klD + 1024 * JMAX;

  // 1. encoder
  k_enc<<<32768, 256, 0, stream>>>(x, en_w, en_b, A);
  // 2. thresholds + key lists + normalized weights (input-independent)
  k_thresh<64, 2, 16, 82, 7938><<<1024, 256, 0, stream>>>(thrD);
  k_thresh<32, 1, 4, 103, 1922><<<1024, 256, 0, stream>>>(thrP);
  k_klist<64, 2, 13, JMAX><<<1024, 256, 0, stream>>>(down_r, thrD, klD, cntD, wlD);
  k_klist<32, 1, 11, JMAX><<<1024, 256, 0, stream>>>(pa_r, thrP, klP, cntP, wlP);
  // 3. down: value ([h][4096][bv]) then batched sparse attention
  k_gemm<1, 1, false, false><<<dim3(512, 4), 256, 0, stream>>>(
      A, down_w, nullptr, nullptr, nullptr, B, 12);
  k_att2<4096, JMAX><<<1024, 256, 0, stream>>>(B, klD, cntD, wlD, lat0);
  // 4. processor blocks: value+res merged; mlp2+res-add+both-biases merged
  for (int i = 0; i < 4; ++i) {
    k_value_res<<<dim3(128, 8), 256, 0, stream>>>(
        lat0, pa_w + (size_t)i * 65536, res_w + (size_t)i * 65536, lat1, lat2);
    k_att2<1024, JMAX><<<1024, 256, 0, stream>>>(lat1, klP, cntP, wlP, lat3);
    k_gemm<0, 0, true, false><<<dim3(128, 4), 256, 0, stream>>>(
        lat3, mlp1_w + (size_t)i * 65536, mlp1_b + i * 256, nullptr, nullptr,
        lat1, 0);
    k_gemm<0, 0, true, true><<<dim3(128, 4), 256, 0, stream>>>(
        lat1, mlp2_w + (size_t)i * 65536, mlp2_b + i * 256, res_b + i * 256,
        lat2, lat0, 0);
  }
  // 5. up: value ([h][1024][bv]) then SEPARABLE dense attention (2 stages)
  k_gemm<1, 1, false, false><<<dim3(128, 4), 256, 0, stream>>>(
      lat0, up_w, nullptr, nullptr, nullptr, lat1, 10);
  k_up_s1<<<dim3(32, 8), 256, 0, stream>>>(lat1, up_r, B);
  k_up_s2<<<dim3(64, 8), 256, 0, stream>>>(B, up_r, A);
  // 6. decoder
  k_gemm<0, 0, true, false><<<dim3(512, 4), 256, 0, stream>>>(
      A, de1_w, de1_b, nullptr, nullptr, B, 0);
  k_fc2<<<8192, 256, 0, stream>>>(B, de2_w, de2_b, out);
}

// Round 5
// 897.438 us; speedup vs baseline: 1.9673x; 1.1375x over previous
//
#include <hip/hip_runtime.h>
#include <math.h>

// ---------------------------------------------------------------------------
// PiTWithCoords: position-attention transformer on fixed grids.
//  * m_dist EXACT in fp32: d_int / 2^S (down S=13, proc S=11, up S=13).
//  * percentile mask == integer threshold on d_int (order statistic).
//  * att weights input- AND batch-independent; down/proc = sparse gather
//    with precomputed normalized weights (k_klist).
//  * UP attention (locality 200 => unmasked) is SEPARABLE (Kronecker):
//    O = Ay*(Ax*V), den = Sx*Sy. 21x FLOP reduction.
//  * R4: sparse attention split per (q,h) with h = blockIdx%8 so each XCD's
//    L2 holds ONE head's value slice (1-4 MB) -> kills the 300 MB overfetch.
// All compute fp32 (no fp32 MFMA on CDNA4). __expf fast paths.
// ---------------------------------------------------------------------------

#define PI_F 3.14159265358979323846f

__device__ __forceinline__ float gelu_f(float x) {
  float u = 0.7978845608028654f * (x + 0.044715f * x * x * x);
  float e = __expf(2.0f * u);
  float t = 1.0f - 2.0f / (e + 1.0f);
  return 0.5f * x * (1.0f + t);
}

__device__ __forceinline__ float head_scale(float r) {
  return tanf(0.25f * PI_F * (1.0f - 1e-7f) * (1.0f + sinf(r)));
}

// ---------------------------------------------------------------------------
__global__ __launch_bounds__(256) void k_enc(const float* __restrict__ x,
                                             const float* __restrict__ w,
                                             const float* __restrict__ b,
                                             float* __restrict__ out) {
  int row = blockIdx.x;
  int o = threadIdx.x;
  float4 xv = *(const float4*)(x + (size_t)row * 4);
  float4 wv = *(const float4*)(w + (size_t)o * 4);
  float s = xv.x * wv.x + xv.y * wv.y + xv.z * wv.z + xv.w * wv.w + b[o];
  out[(size_t)row * 256 + o] = gelu_f(s);
}

// ---------------------------------------------------------------------------
template <int KRES, int CXM, int NPT, int TARGET, int TMAX>
__global__ __launch_bounds__(256) void k_thresh(int* __restrict__ thr) {
  __shared__ int cnt;
  int q = blockIdx.x, tid = threadIdx.x;
  int qx = q & 31, qy = q >> 5;
  int cx = qx * CXM, cy = qy * CXM;
  int d[NPT];
#pragma unroll
  for (int j = 0; j < NPT; ++j) {
    int k = tid * NPT + j;
    int kx = k & (KRES - 1), ky = k / KRES;
    int dx = cx - kx, dy = cy - ky;
    d[j] = dx * dx + dy * dy;
  }
  int lo = 0, hi = TMAX;
  while (lo < hi) {
    int mid = (lo + hi) >> 1;
    if (tid == 0) cnt = 0;
    __syncthreads();
    int c = 0;
#pragma unroll
    for (int j = 0; j < NPT; ++j) c += (d[j] <= mid) ? 1 : 0;
    atomicAdd(&cnt, c);
    __syncthreads();
    int total = cnt;
    __syncthreads();
    if (total >= TARGET) hi = mid; else lo = mid + 1;
  }
  if (tid == 0) thr[q] = lo;
}

// ---------------------------------------------------------------------------
template <int KRES, int CXM, int DSHIFT, int JMAX>
__global__ __launch_bounds__(256) void k_klist(
    const float* __restrict__ rvec, const int* __restrict__ thr,
    int* __restrict__ klist, int* __restrict__ kcnt,
    float* __restrict__ wlist) {
  __shared__ int cntS;
  __shared__ int sidx[JMAX];
  __shared__ int sdv[JMAX];
  __shared__ float wbuf[8][JMAX];
  __shared__ float denS[8];
  int q = blockIdx.x, tid = threadIdx.x;
  int qx = q & 31, qy = q >> 5;
  int cx = qx * CXM, cy = qy * CXM;
  int T = thr[q];
  if (tid == 0) cntS = 0;
  __syncthreads();
  int rad = (int)sqrtf((float)T);
  while ((rad + 1) * (rad + 1) <= T) ++rad;
  while (rad > 0 && rad * rad > T) --rad;
  int x0 = max(0, cx - rad), x1 = min(KRES - 1, cx + rad);
  int y0 = max(0, cy - rad), y1 = min(KRES - 1, cy + rad);
  int W = x1 - x0 + 1, H = y1 - y0 + 1, tot = W * H;
  for (int p = tid; p < tot; p += 256) {
    int kx = x0 + p % W, ky = y0 + p / W;
    int dx = cx - kx, dy = cy - ky;
    int d = dx * dx + dy * dy;
    if (d <= T) {
      int s = atomicAdd(&cntS, 1);
      if (s < JMAX) { sidx[s] = ky * KRES + kx; sdv[s] = d; }
    }
  }
  __syncthreads();
  int cnt = min(cntS, JMAX);
  int h = tid >> 5, j0 = tid & 31;
  float sc = head_scale(rvec[h]) * (1.0f / (float)(1 << DSHIFT));
  float ds = 0.f;
  for (int j = j0; j < cnt; j += 32) {
    float w = __expf(-sc * (float)sdv[j]);
    wbuf[h][j] = w;
    ds += w;
  }
#pragma unroll
  for (int off = 16; off > 0; off >>= 1) ds += __shfl_down(ds, off, 32);
  if (j0 == 0) denS[h] = ds;
  __syncthreads();
  float inv = 1.0f / denS[h];
  for (int j = j0; j < cnt; j += 32)
    wlist[((size_t)h * 1024 + q) * JMAX + j] = wbuf[h][j] * inv;
  if (tid == 0) kcnt[q] = cnt;
  if (h == 0)
    for (int j = j0; j < cnt; j += 32) klist[(size_t)q * JMAX + j] = sidx[j];
}

// ---------------------------------------------------------------------------
// Generic 256-K GEMM, BK=32.
// BL=0: B[k][n]=W[n*256+k]; BL=1: per-head value W[(n>>5)*8192+k*32+(n&31)]
// OL=0: out[m*256+n]; OL=1: out[(((n>>5)*N + r)*8 + b)*32 + (n&31)], N=1<<NS
// ---------------------------------------------------------------------------
template <int BL, int OL, bool GEL, bool ADD>
__global__ __launch_bounds__(256) void k_gemm(const float* __restrict__ A,
                                              const float* __restrict__ W,
                                              const float* __restrict__ bias,
                                              const float* __restrict__ bias2,
                                              const float* __restrict__ addend,
                                              float* __restrict__ out, int NS) {
  __shared__ float As[32][68];
  __shared__ float Bs[32][68];
  int tid = threadIdx.x;
  int m0 = blockIdx.x * 64, n0 = blockIdx.y * 64;
  int lr = tid >> 2, lk = (tid & 3) << 2;
  int ty = tid >> 4, tx = tid & 15;
  float acc[4][4] = {};
  for (int kk = 0; kk < 256; kk += 32) {
#pragma unroll
    for (int half = 0; half < 2; ++half) {
      int k4 = lk + half * 16;
      float4 av = *(const float4*)(A + (size_t)(m0 + lr) * 256 + kk + k4);
      As[k4 + 0][lr] = av.x; As[k4 + 1][lr] = av.y;
      As[k4 + 2][lr] = av.z; As[k4 + 3][lr] = av.w;
      if (BL == 0) {
        float4 wv = *(const float4*)(W + (size_t)(n0 + lr) * 256 + kk + k4);
        Bs[k4 + 0][lr] = wv.x; Bs[k4 + 1][lr] = wv.y;
        Bs[k4 + 2][lr] = wv.z; Bs[k4 + 3][lr] = wv.w;
      } else {
        int k = (tid >> 4) + half * 16, nl = (tid & 15) << 2;
        int ng = n0 + nl;
        float4 wv = *(const float4*)(W + (size_t)(ng >> 5) * 8192 +
                                     (size_t)(kk + k) * 32 + (ng & 31));
        *(float4*)&Bs[k][nl] = wv;
      }
    }
    __syncthreads();
#pragma unroll
    for (int k = 0; k < 32; ++k) {
      float4 a = *(const float4*)&As[k][ty * 4];
      float4 bv = *(const float4*)&Bs[k][tx * 4];
      float ar[4] = {a.x, a.y, a.z, a.w};
      float br[4] = {bv.x, bv.y, bv.z, bv.w};
#pragma unroll
      for (int i = 0; i < 4; ++i)
#pragma unroll
        for (int j = 0; j < 4; ++j) acc[i][j] += ar[i] * br[j];
    }
    __syncthreads();
  }
#pragma unroll
  for (int i = 0; i < 4; ++i) {
    int m = m0 + ty * 4 + i;
#pragma unroll
    for (int j = 0; j < 4; ++j) {
      int n = n0 + tx * 4 + j;
      float c = acc[i][j];
      if (bias) c += bias[n];
      if (bias2) c += bias2[n];
      if (ADD) c += addend[(size_t)m * 256 + n];
      if (GEL) c = gelu_f(c);
      if (OL == 0) {
        out[(size_t)m * 256 + n] = c;
      } else {
        int N = 1 << NS;
        int bb = m >> NS, r = m & (N - 1);
        out[(((size_t)(n >> 5) * N + r) * 8 + bb) * 32 + (n & 31)] = c;
      }
    }
  }
}

// ---------------------------------------------------------------------------
// Merged pa-value + residual GEMM (grid 128,8): y<4 value, y>=4 res_pre.
// ---------------------------------------------------------------------------
__global__ __launch_bounds__(256) void k_value_res(
    const float* __restrict__ A, const float* __restrict__ Wv,
    const float* __restrict__ Wr, float* __restrict__ value,
    float* __restrict__ res_pre) {
  __shared__ float As[32][68];
  __shared__ float Bs[32][68];
  int tid = threadIdx.x;
  bool isv = blockIdx.y < 4;
  int m0 = blockIdx.x * 64;
  int n0 = (isv ? blockIdx.y : blockIdx.y - 4) * 64;
  int lr = tid >> 2, lk = (tid & 3) << 2;
  int ty = tid >> 4, tx = tid & 15;
  float acc[4][4] = {};
  for (int kk = 0; kk < 256; kk += 32) {
#pragma unroll
    for (int half = 0; half < 2; ++half) {
      int k4 = lk + half * 16;
      float4 av = *(const float4*)(A + (size_t)(m0 + lr) * 256 + kk + k4);
      As[k4 + 0][lr] = av.x; As[k4 + 1][lr] = av.y;
      As[k4 + 2][lr] = av.z; As[k4 + 3][lr] = av.w;
      if (isv) {
        int k = (tid >> 4) + half * 16, nl = (tid & 15) << 2;
        int ng = n0 + nl;
        float4 wv = *(const float4*)(Wv + (size_t)(ng >> 5) * 8192 +
                                     (size_t)(kk + k) * 32 + (ng & 31));
        *(float4*)&Bs[k][nl] = wv;
      } else {
        float4 wv = *(const float4*)(Wr + (size_t)(n0 + lr) * 256 + kk + k4);
        Bs[k4 + 0][lr] = wv.x; Bs[k4 + 1][lr] = wv.y;
        Bs[k4 + 2][lr] = wv.z; Bs[k4 + 3][lr] = wv.w;
      }
    }
    __syncthreads();
#pragma unroll
    for (int k = 0; k < 32; ++k) {
      float4 a = *(const float4*)&As[k][ty * 4];
      float4 bv = *(const float4*)&Bs[k][tx * 4];
      float ar[4] = {a.x, a.y, a.z, a.w};
      float br[4] = {bv.x, bv.y, bv.z, bv.w};
#pragma unroll
      for (int i = 0; i < 4; ++i)
#pragma unroll
        for (int j = 0; j < 4; ++j) acc[i][j] += ar[i] * br[j];
    }
    __syncthreads();
  }
#pragma unroll
  for (int i = 0; i < 4; ++i) {
    int m = m0 + ty * 4 + i;
#pragma unroll
    for (int j = 0; j < 4; ++j) {
      int n = n0 + tx * 4 + j;
      float c = acc[i][j];
      if (isv) {
        int bb = m >> 10, r = m & 1023;
        value[(((size_t)(n >> 5) * 1024 + r) * 8 + bb) * 32 + (n & 31)] = c;
      } else {
        res_pre[(size_t)m * 256 + n] = c;
      }
    }
  }
}

// ---------------------------------------------------------------------------
// Sparse attention, one block per (q, h) with h = blockIdx%8 so all blocks
// of a head land on one XCD (round-robin dispatch heuristic): per-XCD L2
// working set = one head's value slice (proc 1 MB / down 4 MB). Thread =
// (b,v) channel: the 256 threads read each 1 KB row slice exactly once,
// fully coalesced. Weights precomputed & normalized (k_klist).
// ---------------------------------------------------------------------------
template <int NK, int JMAX>
__global__ __launch_bounds__(256) void k_att2h(
    const float* __restrict__ value,   // [h][NK][b*32+v]
    const int* __restrict__ klist, const int* __restrict__ kcnt,
    const float* __restrict__ wlist,
    float* __restrict__ out /* [8,1024,256] */) {
  __shared__ int kls[JMAX];
  __shared__ float wls[JMAX];
  int blk = blockIdx.x;
  int h = blk & 7, q = blk >> 3;
  int tid = threadIdx.x;
  int cnt = kcnt[q];
  for (int i = tid; i < cnt; i += 256) {
    kls[i] = klist[(size_t)q * JMAX + i];
    wls[i] = wlist[((size_t)h * 1024 + q) * JMAX + i];
  }
  __syncthreads();
  const float* vb = value + (size_t)h * NK * 256 + tid;
  float a0 = 0.f, a1 = 0.f, a2 = 0.f, a3 = 0.f;
  int j = 0;
  for (; j + 4 <= cnt; j += 4) {
    float v0 = vb[(size_t)kls[j + 0] * 256];
    float v1 = vb[(size_t)kls[j + 1] * 256];
    float v2 = vb[(size_t)kls[j + 2] * 256];
    float v3 = vb[(size_t)kls[j + 3] * 256];
    a0 += wls[j + 0] * v0;
    a1 += wls[j + 1] * v1;
    a2 += wls[j + 2] * v2;
    a3 += wls[j + 3] * v3;
  }
  for (; j < cnt; ++j) a0 += wls[j] * vb[(size_t)kls[j] * 256];
  float acc = (a0 + a1) + (a2 + a3);
  int b = tid >> 5, v = tid & 31;
  out[((size_t)b * 1024 + q) * 256 + h * 32 + v] = gelu_f(acc);
}

// ---------------------------------------------------------------------------
// Separable up-attention, stage 1: T[h][qx][ky][bv] = sum_kx Ax[qx][kx]*V.
// ---------------------------------------------------------------------------
__global__ __launch_bounds__(256) void k_up_s1(
    const float* __restrict__ value,  // [h][1024][bv]
    const float* __restrict__ rvec, float* __restrict__ T) {
  __shared__ float AxL[64][33];
  int ky = blockIdx.x, h = blockIdx.y, tid = threadIdx.x;
  float sc = head_scale(rvec[h]) * (1.0f / 8192.0f);
  float v[32];
  const float* vb = value + ((size_t)h * 1024 + ky * 32) * 256 + tid;
#pragma unroll
  for (int kx = 0; kx < 32; ++kx) v[kx] = vb[kx * 256];
  if (tid < 64) {
    int qx = tid, dxmin = qx & 1;
    for (int kx = 0; kx < 32; ++kx) {
      int dx = qx - 2 * kx;
      AxL[qx][kx] = __expf(-sc * (float)(dx * dx - dxmin));
    }
  }
  __syncthreads();
  float* tb = T + (((size_t)h * 64) * 32 + ky) * 256 + tid;
  for (int qx = 0; qx < 64; ++qx) {
    float acc = 0.f;
#pragma unroll
    for (int kx = 0; kx < 32; ++kx) acc += AxL[qx][kx] * v[kx];
    tb[(size_t)qx * 32 * 256] = acc;
  }
}

// ---------------------------------------------------------------------------
// Separable up-attention, stage 2.
// ---------------------------------------------------------------------------
__global__ __launch_bounds__(256) void k_up_s2(
    const float* __restrict__ T, const float* __restrict__ rvec,
    float* __restrict__ out /* [8,4096,256] */) {
  __shared__ float AyL[64][33];
  __shared__ float Sy[64];
  __shared__ float SxS;
  int qx = blockIdx.x, h = blockIdx.y, tid = threadIdx.x;
  float sc = head_scale(rvec[h]) * (1.0f / 8192.0f);
  float t[32];
  const float* tb = T + ((size_t)h * 64 + qx) * 32 * 256 + tid;
#pragma unroll
  for (int ky = 0; ky < 32; ++ky) t[ky] = tb[ky * 256];
  if (tid < 64) {
    int qy = tid, dymin = qy & 1;
    float s = 0.f;
    for (int ky = 0; ky < 32; ++ky) {
      int dy = qy - 2 * ky;
      float e = __expf(-sc * (float)(dy * dy - dymin));
      AyL[qy][ky] = e;
      s += e;
    }
    Sy[qy] = s;
  } else if (tid >= 64 && tid < 96) {
    int kx = tid - 64, dxmin = qx & 1;
    int dx = qx - 2 * kx;
    float e = __expf(-sc * (float)(dx * dx - dxmin));
#pragma unroll
    for (int off = 16; off > 0; off >>= 1) e += __shfl_down(e, off, 32);
    if (kx == 0) SxS = e;
  }
  __syncthreads();
  float invSx = 1.0f / SxS;
  int b = tid >> 5, v = tid & 31;
  float* ob = out + ((size_t)b * 4096 + qx) * 256 + h * 32 + v;
  for (int qy = 0; qy < 64; ++qy) {
    float acc = 0.f;
#pragma unroll
    for (int ky = 0; ky < 32; ++ky) acc += AyL[qy][ky] * t[ky];
    float o = gelu_f(acc * invSx / Sy[qy]);
    ob[(size_t)qy * 64 * 256] = o;
  }
}

// ---------------------------------------------------------------------------
__global__ __launch_bounds__(256) void k_fc2(const float* __restrict__ h,
                                             const float* __restrict__ w,
                                             const float* __restrict__ b,
                                             float* __restrict__ out) {
  int row = blockIdx.x * 4 + (threadIdx.x >> 6);
  int lane = threadIdx.x & 63;
  float4 hv = *(const float4*)(h + (size_t)row * 256 + lane * 4);
  float4 wv = *(const float4*)(w + lane * 4);
  float s = hv.x * wv.x + hv.y * wv.y + hv.z * wv.z + hv.w * wv.w;
#pragma unroll
  for (int off = 32; off > 0; off >>= 1) s += __shfl_down(s, off, 64);
  if (lane == 0) out[row] = s + b[0];
}

// ---------------------------------------------------------------------------
extern "C" void kernel_launch(void* const* d_in, const int* in_sizes, int n_in,
                              void* d_out, int out_size, void* d_ws,
                              size_t ws_size, hipStream_t stream) {
  const float* x      = (const float*)d_in[0];
  const float* en_w   = (const float*)d_in[1];
  const float* en_b   = (const float*)d_in[2];
  const float* down_r = (const float*)d_in[3];
  const float* down_w = (const float*)d_in[4];
  const float* pa_r   = (const float*)d_in[5];
  const float* pa_w   = (const float*)d_in[6];
  const float* mlp1_w = (const float*)d_in[7];
  const float* mlp1_b = (const float*)d_in[8];
  const float* mlp2_w = (const float*)d_in[9];
  const float* mlp2_b = (const float*)d_in[10];
  const float* res_w  = (const float*)d_in[11];
  const float* res_b  = (const float*)d_in[12];
  const float* up_r   = (const float*)d_in[13];
  const float* up_w   = (const float*)d_in[14];
  const float* de1_w  = (const float*)d_in[15];
  const float* de1_b  = (const float*)d_in[16];
  const float* de2_w  = (const float*)d_in[17];
  const float* de2_b  = (const float*)d_in[18];
  float* out = (float*)d_out;

  constexpr int JMAX = 144;
  float* ws = (float*)d_ws;
  float* A = ws;                  // [8,4096,256] enc out; later up-att out
  float* B = A + 8388608;         // [h][4096][bv] value_down; T; dec hidden
  float* lat0 = B + 8388608;      // h in/out of processor iters
  float* lat1 = lat0 + 2097152;   // value / mlp1-out
  float* lat2 = lat1 + 2097152;   // res_pre
  float* lat3 = lat2 + 2097152;   // pa_out
  float* wlD = lat3 + 2097152;    // [8,1024,JMAX]
  float* wlP = wlD + 8 * 1024 * JMAX;
  int* thrD = (int*)(wlP + 8 * 1024 * JMAX);
  int* thrP = thrD + 1024;
  int* cntD = thrP + 1024;
  int* cntP = cntD + 1024;
  int* klD = cntP + 1024;         // [1024,JMAX]
  int* klP = klD + 1024 * JMAX;

  // 1. encoder
  k_enc<<<32768, 256, 0, stream>>>(x, en_w, en_b, A);
  // 2. thresholds + key lists + normalized weights (input-independent)
  k_thresh<64, 2, 16, 82, 7938><<<1024, 256, 0, stream>>>(thrD);
  k_thresh<32, 1, 4, 103, 1922><<<1024, 256, 0, stream>>>(thrP);
  k_klist<64, 2, 13, JMAX><<<1024, 256, 0, stream>>>(down_r, thrD, klD, cntD, wlD);
  k_klist<32, 1, 11, JMAX><<<1024, 256, 0, stream>>>(pa_r, thrP, klP, cntP, wlP);
  // 3. down: value ([h][4096][bv]) then per-(q,h) sparse attention
  k_gemm<1, 1, false, false><<<dim3(512, 4), 256, 0, stream>>>(
      A, down_w, nullptr, nullptr, nullptr, B, 12);
  k_att2h<4096, JMAX><<<8192, 256, 0, stream>>>(B, klD, cntD, wlD, lat0);
  // 4. processor blocks: value+res merged; mlp2+res-add+both-biases merged
  for (int i = 0; i < 4; ++i) {
    k_value_res<<<dim3(128, 8), 256, 0, stream>>>(
        lat0, pa_w + (size_t)i * 65536, res_w + (size_t)i * 65536, lat1, lat2);
    k_att2h<1024, JMAX><<<8192, 256, 0, stream>>>(lat1, klP, cntP, wlP, lat3);
    k_gemm<0, 0, true, false><<<dim3(128, 4), 256, 0, stream>>>(
        lat3, mlp1_w + (size_t)i * 65536, mlp1_b + i * 256, nullptr, nullptr,
        lat1, 0);
    k_gemm<0, 0, true, true><<<dim3(128, 4), 256, 0, stream>>>(
        lat1, mlp2_w + (size_t)i * 65536, mlp2_b + i * 256, res_b + i * 256,
        lat2, lat0, 0);
  }
  // 5. up: value ([h][1024][bv]) then SEPARABLE dense attention (2 stages)
  k_gemm<1, 1, false, false><<<dim3(128, 4), 256, 0, stream>>>(
      lat0, up_w, nullptr, nullptr, nullptr, lat1, 10);
  k_up_s1<<<dim3(32, 8), 256, 0, stream>>>(lat1, up_r, B);
  k_up_s2<<<dim3(64, 8), 256, 0, stream>>>(B, up_r, A);
  // 6. decoder
  k_gemm<0, 0, true, false><<<dim3(512, 4), 256, 0, stream>>>(
      A, de1_w, de1_b, nullptr, nullptr, B, 0);
  k_fc2<<<8192, 256, 0, stream>>>(B, de2_w, de2_b, out);
}

// Round 6
// 845.681 us; speedup vs baseline: 2.0877x; 1.0612x over previous
//
#include <hip/hip_runtime.h>
#include <math.h>

// ---------------------------------------------------------------------------
// PiTWithCoords: position-attention transformer on fixed grids.
//  * m_dist EXACT in fp32: d_int / 2^S (down S=13, proc S=11, up S=13).
//  * percentile mask == integer threshold on d_int (order statistic).
//  * att weights input/batch-independent; down/proc = sparse gather with
//    precomputed normalized weights; h=blockIdx%8 XCD-locality split.
//  * UP attention separable (Kronecker): O = Ay*(Ax*V), den = Sx*Sy.
//  * R5: big GEMMs (down-value, dec-fc1) -> split-bf16 MFMA (a=hi+lo,
//    3x mfma_f32_16x16x32_bf16). Weights are 1/16-scaled => dot error
//    ~4e-6, far under the 1.24e-4 threshold. Producers emit hi/lo bf16.
// ---------------------------------------------------------------------------

#define PI_F 3.14159265358979323846f

typedef __attribute__((ext_vector_type(8))) short short8;
typedef __attribute__((ext_vector_type(4))) float float4v;

__device__ __forceinline__ float gelu_f(float x) {
  float u = 0.7978845608028654f * (x + 0.044715f * x * x * x);
  float e = __expf(2.0f * u);
  float t = 1.0f - 2.0f / (e + 1.0f);
  return 0.5f * x * (1.0f + t);
}

__device__ __forceinline__ float head_scale(float r) {
  return tanf(0.25f * PI_F * (1.0f - 1e-7f) * (1.0f + sinf(r)));
}

__device__ __forceinline__ unsigned short f2bf(float f) {
  union { float f; unsigned u; } c; c.f = f;
  unsigned u = c.u + 0x7FFFu + ((c.u >> 16) & 1u);
  return (unsigned short)(u >> 16);
}
__device__ __forceinline__ float bf2f(unsigned short h) {
  union { unsigned u; float f; } c; c.u = ((unsigned)h) << 16;
  return c.f;
}
__device__ __forceinline__ void split_bf(float f, unsigned short& hi,
                                         unsigned short& lo) {
  hi = f2bf(f);
  lo = f2bf(f - bf2f(hi));
}

// ---------------------------------------------------------------------------
// Encoder -> bf16 hi/lo (feeds only the down-value MFMA GEMM).
// ---------------------------------------------------------------------------
__global__ __launch_bounds__(256) void k_enc(
    const float* __restrict__ x, const float* __restrict__ w,
    const float* __restrict__ b, unsigned short* __restrict__ ahi,
    unsigned short* __restrict__ alo) {
  int row = blockIdx.x;
  int o = threadIdx.x;
  float4 xv = *(const float4*)(x + (size_t)row * 4);
  float4 wv = *(const float4*)(w + (size_t)o * 4);
  float s = xv.x * wv.x + xv.y * wv.y + xv.z * wv.z + xv.w * wv.w + b[o];
  s = gelu_f(s);
  unsigned short hi, lo;
  split_bf(s, hi, lo);
  ahi[(size_t)row * 256 + o] = hi;
  alo[(size_t)row * 256 + o] = lo;
}

// ---------------------------------------------------------------------------
// Weight split kernels. [n][k] bf16 hi/lo output layout.
// ---------------------------------------------------------------------------
__global__ __launch_bounds__(256) void k_split_w(
    const float* __restrict__ w, unsigned short* __restrict__ whi,
    unsigned short* __restrict__ wlo) {
  int i = blockIdx.x * 256 + threadIdx.x;  // = n*256+k, direct copy
  unsigned short hi, lo;
  split_bf(w[i], hi, lo);
  whi[i] = hi;
  wlo[i] = lo;
}
__global__ __launch_bounds__(256) void k_split_wv(
    const float* __restrict__ w,  // per-head [(n>>5)*8192 + k*32 + (n&31)]
    unsigned short* __restrict__ whi, unsigned short* __restrict__ wlo) {
  int i = blockIdx.x * 256 + threadIdx.x;
  int n = i >> 8, k = i & 255;
  float f = w[(size_t)(n >> 5) * 8192 + (size_t)k * 32 + (n & 31)];
  unsigned short hi, lo;
  split_bf(f, hi, lo);
  whi[i] = hi;  // [n][k]
  wlo[i] = lo;
}

// ---------------------------------------------------------------------------
// Split-bf16 MFMA GEMM: out = epi(A * W^T [+ bias]), A [M,256], W [256(n),256(k)]
// in bf16 hi/lo pairs. Tile 128x128, 4 waves = 2x2 of 64x64, BK=32, K=256.
// Per product: hi*hi + hi*lo + lo*hi (lo*lo dropped, ~2^-18 relative).
// OL=0: out[m*256+n] fp32. OL=1: value layout (down): m=b*4096+r ->
//       out[(((n>>5)*4096 + r)*8 + b)*32 + (n&31)].
// ---------------------------------------------------------------------------
template <int OL, bool GEL>
__global__ __launch_bounds__(256) void k_mfma(
    const unsigned short* __restrict__ Ahi, const unsigned short* __restrict__ Alo,
    const unsigned short* __restrict__ Whi, const unsigned short* __restrict__ Wlo,
    const float* __restrict__ bias, float* __restrict__ out) {
  __shared__ unsigned short Ah[128][40], Al[128][40];
  __shared__ unsigned short Bh[128][40], Bl[128][40];
  int tid = threadIdx.x;
  int m0 = blockIdx.x * 128, n0 = blockIdx.y * 128;
  int w = tid >> 6, lane = tid & 63;
  int wm = (w >> 1) * 64, wn = (w & 1) * 64;
  int quad = lane >> 4, l16 = lane & 15;
  float4v acc[4][4];
#pragma unroll
  for (int i = 0; i < 4; ++i)
#pragma unroll
    for (int j = 0; j < 4; ++j) acc[i][j] = (float4v)0.0f;

  int srow = tid >> 1, skq = (tid & 1) * 16;  // staging: row + 16-ushort half
  for (int kk = 0; kk < 256; kk += 32) {
    {
      size_t ga = (size_t)(m0 + srow) * 256 + kk + skq;
      const uint4* pah = (const uint4*)(Ahi + ga);
      const uint4* pal = (const uint4*)(Alo + ga);
      *(uint4*)&Ah[srow][skq] = pah[0];
      *(uint4*)&Ah[srow][skq + 8] = pah[1];
      *(uint4*)&Al[srow][skq] = pal[0];
      *(uint4*)&Al[srow][skq + 8] = pal[1];
      size_t gb = (size_t)(n0 + srow) * 256 + kk + skq;
      const uint4* pbh = (const uint4*)(Whi + gb);
      const uint4* pbl = (const uint4*)(Wlo + gb);
      *(uint4*)&Bh[srow][skq] = pbh[0];
      *(uint4*)&Bh[srow][skq + 8] = pbh[1];
      *(uint4*)&Bl[srow][skq] = pbl[0];
      *(uint4*)&Bl[srow][skq + 8] = pbl[1];
    }
    __syncthreads();
    short8 ah[4], al[4], bh[4], bl[4];
#pragma unroll
    for (int s = 0; s < 4; ++s) {
      ah[s] = *(const short8*)&Ah[wm + s * 16 + l16][quad * 8];
      al[s] = *(const short8*)&Al[wm + s * 16 + l16][quad * 8];
      bh[s] = *(const short8*)&Bh[wn + s * 16 + l16][quad * 8];
      bl[s] = *(const short8*)&Bl[wn + s * 16 + l16][quad * 8];
    }
#pragma unroll
    for (int ms = 0; ms < 4; ++ms)
#pragma unroll
      for (int ns = 0; ns < 4; ++ns) {
        acc[ms][ns] = __builtin_amdgcn_mfma_f32_16x16x32_bf16(
            ah[ms], bh[ns], acc[ms][ns], 0, 0, 0);
        acc[ms][ns] = __builtin_amdgcn_mfma_f32_16x16x32_bf16(
            ah[ms], bl[ns], acc[ms][ns], 0, 0, 0);
        acc[ms][ns] = __builtin_amdgcn_mfma_f32_16x16x32_bf16(
            al[ms], bh[ns], acc[ms][ns], 0, 0, 0);
      }
    __syncthreads();
  }
#pragma unroll
  for (int ms = 0; ms < 4; ++ms) {
#pragma unroll
    for (int ns = 0; ns < 4; ++ns) {
      int n = n0 + wn + ns * 16 + l16;
      float bv = bias ? bias[n] : 0.0f;
#pragma unroll
      for (int r = 0; r < 4; ++r) {
        int m = m0 + wm + ms * 16 + quad * 4 + r;
        float c = acc[ms][ns][r] + bv;
        if (GEL) c = gelu_f(c);
        if (OL == 0) {
          out[(size_t)m * 256 + n] = c;
        } else {
          int bb = m >> 12, rr = m & 4095;
          out[(((size_t)(n >> 5) * 4096 + rr) * 8 + bb) * 32 + (n & 31)] = c;
        }
      }
    }
  }
}

// ---------------------------------------------------------------------------
template <int KRES, int CXM, int NPT, int TARGET, int TMAX>
__global__ __launch_bounds__(256) void k_thresh(int* __restrict__ thr) {
  __shared__ int cnt;
  int q = blockIdx.x, tid = threadIdx.x;
  int qx = q & 31, qy = q >> 5;
  int cx = qx * CXM, cy = qy * CXM;
  int d[NPT];
#pragma unroll
  for (int j = 0; j < NPT; ++j) {
    int k = tid * NPT + j;
    int kx = k & (KRES - 1), ky = k / KRES;
    int dx = cx - kx, dy = cy - ky;
    d[j] = dx * dx + dy * dy;
  }
  int lo = 0, hi = TMAX;
  while (lo < hi) {
    int mid = (lo + hi) >> 1;
    if (tid == 0) cnt = 0;
    __syncthreads();
    int c = 0;
#pragma unroll
    for (int j = 0; j < NPT; ++j) c += (d[j] <= mid) ? 1 : 0;
    atomicAdd(&cnt, c);
    __syncthreads();
    int total = cnt;
    __syncthreads();
    if (total >= TARGET) hi = mid; else lo = mid + 1;
  }
  if (tid == 0) thr[q] = lo;
}

// ---------------------------------------------------------------------------
template <int KRES, int CXM, int DSHIFT, int JMAX>
__global__ __launch_bounds__(256) void k_klist(
    const float* __restrict__ rvec, const int* __restrict__ thr,
    int* __restrict__ klist, int* __restrict__ kcnt,
    float* __restrict__ wlist) {
  __shared__ int cntS;
  __shared__ int sidx[JMAX];
  __shared__ int sdv[JMAX];
  __shared__ float wbuf[8][JMAX];
  __shared__ float denS[8];
  int q = blockIdx.x, tid = threadIdx.x;
  int qx = q & 31, qy = q >> 5;
  int cx = qx * CXM, cy = qy * CXM;
  int T = thr[q];
  if (tid == 0) cntS = 0;
  __syncthreads();
  int rad = (int)sqrtf((float)T);
  while ((rad + 1) * (rad + 1) <= T) ++rad;
  while (rad > 0 && rad * rad > T) --rad;
  int x0 = max(0, cx - rad), x1 = min(KRES - 1, cx + rad);
  int y0 = max(0, cy - rad), y1 = min(KRES - 1, cy + rad);
  int W = x1 - x0 + 1, H = y1 - y0 + 1, tot = W * H;
  for (int p = tid; p < tot; p += 256) {
    int kx = x0 + p % W, ky = y0 + p / W;
    int dx = cx - kx, dy = cy - ky;
    int d = dx * dx + dy * dy;
    if (d <= T) {
      int s = atomicAdd(&cntS, 1);
      if (s < JMAX) { sidx[s] = ky * KRES + kx; sdv[s] = d; }
    }
  }
  __syncthreads();
  int cnt = min(cntS, JMAX);
  int h = tid >> 5, j0 = tid & 31;
  float sc = head_scale(rvec[h]) * (1.0f / (float)(1 << DSHIFT));
  float ds = 0.f;
  for (int j = j0; j < cnt; j += 32) {
    float w = __expf(-sc * (float)sdv[j]);
    wbuf[h][j] = w;
    ds += w;
  }
#pragma unroll
  for (int off = 16; off > 0; off >>= 1) ds += __shfl_down(ds, off, 32);
  if (j0 == 0) denS[h] = ds;
  __syncthreads();
  float inv = 1.0f / denS[h];
  for (int j = j0; j < cnt; j += 32)
    wlist[((size_t)h * 1024 + q) * JMAX + j] = wbuf[h][j] * inv;
  if (tid == 0) kcnt[q] = cnt;
  if (h == 0)
    for (int j = j0; j < cnt; j += 32) klist[(size_t)q * JMAX + j] = sidx[j];
}

// ---------------------------------------------------------------------------
// Generic 256-K fp32 GEMM, BK=32 (processor-sized dispatches).
// ---------------------------------------------------------------------------
template <int BL, int OL, bool GEL, bool ADD>
__global__ __launch_bounds__(256) void k_gemm(const float* __restrict__ A,
                                              const float* __restrict__ W,
                                              const float* __restrict__ bias,
                                              const float* __restrict__ bias2,
                                              const float* __restrict__ addend,
                                              float* __restrict__ out, int NS) {
  __shared__ float As[32][68];
  __shared__ float Bs[32][68];
  int tid = threadIdx.x;
  int m0 = blockIdx.x * 64, n0 = blockIdx.y * 64;
  int lr = tid >> 2, lk = (tid & 3) << 2;
  int ty = tid >> 4, tx = tid & 15;
  float acc[4][4] = {};
  for (int kk = 0; kk < 256; kk += 32) {
#pragma unroll
    for (int half = 0; half < 2; ++half) {
      int k4 = lk + half * 16;
      float4 av = *(const float4*)(A + (size_t)(m0 + lr) * 256 + kk + k4);
      As[k4 + 0][lr] = av.x; As[k4 + 1][lr] = av.y;
      As[k4 + 2][lr] = av.z; As[k4 + 3][lr] = av.w;
      if (BL == 0) {
        float4 wv = *(const float4*)(W + (size_t)(n0 + lr) * 256 + kk + k4);
        Bs[k4 + 0][lr] = wv.x; Bs[k4 + 1][lr] = wv.y;
        Bs[k4 + 2][lr] = wv.z; Bs[k4 + 3][lr] = wv.w;
      } else {
        int k = (tid >> 4) + half * 16, nl = (tid & 15) << 2;
        int ng = n0 + nl;
        float4 wv = *(const float4*)(W + (size_t)(ng >> 5) * 8192 +
                                     (size_t)(kk + k) * 32 + (ng & 31));
        *(float4*)&Bs[k][nl] = wv;
      }
    }
    __syncthreads();
#pragma unroll
    for (int k = 0; k < 32; ++k) {
      float4 a = *(const float4*)&As[k][ty * 4];
      float4 bv = *(const float4*)&Bs[k][tx * 4];
      float ar[4] = {a.x, a.y, a.z, a.w};
      float br[4] = {bv.x, bv.y, bv.z, bv.w};
#pragma unroll
      for (int i = 0; i < 4; ++i)
#pragma unroll
        for (int j = 0; j < 4; ++j) acc[i][j] += ar[i] * br[j];
    }
    __syncthreads();
  }
#pragma unroll
  for (int i = 0; i < 4; ++i) {
    int m = m0 + ty * 4 + i;
#pragma unroll
    for (int j = 0; j < 4; ++j) {
      int n = n0 + tx * 4 + j;
      float c = acc[i][j];
      if (bias) c += bias[n];
      if (bias2) c += bias2[n];
      if (ADD) c += addend[(size_t)m * 256 + n];
      if (GEL) c = gelu_f(c);
      if (OL == 0) {
        out[(size_t)m * 256 + n] = c;
      } else {
        int N = 1 << NS;
        int bb = m >> NS, r = m & (N - 1);
        out[(((size_t)(n >> 5) * N + r) * 8 + bb) * 32 + (n & 31)] = c;
      }
    }
  }
}

// ---------------------------------------------------------------------------
// Merged pa-value + residual GEMM (grid 128,8): y<4 value, y>=4 res_pre.
// ---------------------------------------------------------------------------
__global__ __launch_bounds__(256) void k_value_res(
    const float* __restrict__ A, const float* __restrict__ Wv,
    const float* __restrict__ Wr, float* __restrict__ value,
    float* __restrict__ res_pre) {
  __shared__ float As[32][68];
  __shared__ float Bs[32][68];
  int tid = threadIdx.x;
  bool isv = blockIdx.y < 4;
  int m0 = blockIdx.x * 64;
  int n0 = (isv ? blockIdx.y : blockIdx.y - 4) * 64;
  int lr = tid >> 2, lk = (tid & 3) << 2;
  int ty = tid >> 4, tx = tid & 15;
  float acc[4][4] = {};
  for (int kk = 0; kk < 256; kk += 32) {
#pragma unroll
    for (int half = 0; half < 2; ++half) {
      int k4 = lk + half * 16;
      float4 av = *(const float4*)(A + (size_t)(m0 + lr) * 256 + kk + k4);
      As[k4 + 0][lr] = av.x; As[k4 + 1][lr] = av.y;
      As[k4 + 2][lr] = av.z; As[k4 + 3][lr] = av.w;
      if (isv) {
        int k = (tid >> 4) + half * 16, nl = (tid & 15) << 2;
        int ng = n0 + nl;
        float4 wv = *(const float4*)(Wv + (size_t)(ng >> 5) * 8192 +
                                     (size_t)(kk + k) * 32 + (ng & 31));
        *(float4*)&Bs[k][nl] = wv;
      } else {
        float4 wv = *(const float4*)(Wr + (size_t)(n0 + lr) * 256 + kk + k4);
        Bs[k4 + 0][lr] = wv.x; Bs[k4 + 1][lr] = wv.y;
        Bs[k4 + 2][lr] = wv.z; Bs[k4 + 3][lr] = wv.w;
      }
    }
    __syncthreads();
#pragma unroll
    for (int k = 0; k < 32; ++k) {
      float4 a = *(const float4*)&As[k][ty * 4];
      float4 bv = *(const float4*)&Bs[k][tx * 4];
      float ar[4] = {a.x, a.y, a.z, a.w};
      float br[4] = {bv.x, bv.y, bv.z, bv.w};
#pragma unroll
      for (int i = 0; i < 4; ++i)
#pragma unroll
        for (int j = 0; j < 4; ++j) acc[i][j] += ar[i] * br[j];
    }
    __syncthreads();
  }
#pragma unroll
  for (int i = 0; i < 4; ++i) {
    int m = m0 + ty * 4 + i;
#pragma unroll
    for (int j = 0; j < 4; ++j) {
      int n = n0 + tx * 4 + j;
      float c = acc[i][j];
      if (isv) {
        int bb = m >> 10, r = m & 1023;
        value[(((size_t)(n >> 5) * 1024 + r) * 8 + bb) * 32 + (n & 31)] = c;
      } else {
        res_pre[(size_t)m * 256 + n] = c;
      }
    }
  }
}

// ---------------------------------------------------------------------------
// Sparse attention, one block per (q, h), h = blockIdx%8 (XCD locality).
// ---------------------------------------------------------------------------
template <int NK, int JMAX>
__global__ __launch_bounds__(256) void k_att2h(
    const float* __restrict__ value,   // [h][NK][b*32+v]
    const int* __restrict__ klist, const int* __restrict__ kcnt,
    const float* __restrict__ wlist,
    float* __restrict__ out /* [8,1024,256] */) {
  __shared__ int kls[JMAX];
  __shared__ float wls[JMAX];
  int blk = blockIdx.x;
  int h = blk & 7, q = blk >> 3;
  int tid = threadIdx.x;
  int cnt = kcnt[q];
  for (int i = tid; i < cnt; i += 256) {
    kls[i] = klist[(size_t)q * JMAX + i];
    wls[i] = wlist[((size_t)h * 1024 + q) * JMAX + i];
  }
  __syncthreads();
  const float* vb = value + (size_t)h * NK * 256 + tid;
  float a0 = 0.f, a1 = 0.f, a2 = 0.f, a3 = 0.f;
  int j = 0;
  for (; j + 4 <= cnt; j += 4) {
    float v0 = vb[(size_t)kls[j + 0] * 256];
    float v1 = vb[(size_t)kls[j + 1] * 256];
    float v2 = vb[(size_t)kls[j + 2] * 256];
    float v3 = vb[(size_t)kls[j + 3] * 256];
    a0 += wls[j + 0] * v0;
    a1 += wls[j + 1] * v1;
    a2 += wls[j + 2] * v2;
    a3 += wls[j + 3] * v3;
  }
  for (; j < cnt; ++j) a0 += wls[j] * vb[(size_t)kls[j] * 256];
  float acc = (a0 + a1) + (a2 + a3);
  int b = tid >> 5, v = tid & 31;
  out[((size_t)b * 1024 + q) * 256 + h * 32 + v] = gelu_f(acc);
}

// ---------------------------------------------------------------------------
// Separable up-attention, stage 1.
// ---------------------------------------------------------------------------
__global__ __launch_bounds__(256) void k_up_s1(
    const float* __restrict__ value,  // [h][1024][bv]
    const float* __restrict__ rvec, float* __restrict__ T) {
  __shared__ float AxL[64][33];
  int ky = blockIdx.x, h = blockIdx.y, tid = threadIdx.x;
  float sc = head_scale(rvec[h]) * (1.0f / 8192.0f);
  float v[32];
  const float* vb = value + ((size_t)h * 1024 + ky * 32) * 256 + tid;
#pragma unroll
  for (int kx = 0; kx < 32; ++kx) v[kx] = vb[kx * 256];
  if (tid < 64) {
    int qx = tid, dxmin = qx & 1;
    for (int kx = 0; kx < 32; ++kx) {
      int dx = qx - 2 * kx;
      AxL[qx][kx] = __expf(-sc * (float)(dx * dx - dxmin));
    }
  }
  __syncthreads();
  float* tb = T + (((size_t)h * 64) * 32 + ky) * 256 + tid;
  for (int qx = 0; qx < 64; ++qx) {
    float acc = 0.f;
#pragma unroll
    for (int kx = 0; kx < 32; ++kx) acc += AxL[qx][kx] * v[kx];
    tb[(size_t)qx * 32 * 256] = acc;
  }
}

// ---------------------------------------------------------------------------
// Separable up-attention, stage 2 -> bf16 hi/lo (feeds only dec-fc1 MFMA).
// ---------------------------------------------------------------------------
__global__ __launch_bounds__(256) void k_up_s2(
    const float* __restrict__ T, const float* __restrict__ rvec,
    unsigned short* __restrict__ ohi, unsigned short* __restrict__ olo) {
  __shared__ float AyL[64][33];
  __shared__ float Sy[64];
  __shared__ float SxS;
  int qx = blockIdx.x, h = blockIdx.y, tid = threadIdx.x;
  float sc = head_scale(rvec[h]) * (1.0f / 8192.0f);
  float t[32];
  const float* tb = T + ((size_t)h * 64 + qx) * 32 * 256 + tid;
#pragma unroll
  for (int ky = 0; ky < 32; ++ky) t[ky] = tb[ky * 256];
  if (tid < 64) {
    int qy = tid, dymin = qy & 1;
    float s = 0.f;
    for (int ky = 0; ky < 32; ++ky) {
      int dy = qy - 2 * ky;
      float e = __expf(-sc * (float)(dy * dy - dymin));
      AyL[qy][ky] = e;
      s += e;
    }
    Sy[qy] = s;
  } else if (tid >= 64 && tid < 96) {
    int kx = tid - 64, dxmin = qx & 1;
    int dx = qx - 2 * kx;
    float e = __expf(-sc * (float)(dx * dx - dxmin));
#pragma unroll
    for (int off = 16; off > 0; off >>= 1) e += __shfl_down(e, off, 32);
    if (kx == 0) SxS = e;
  }
  __syncthreads();
  float invSx = 1.0f / SxS;
  int b = tid >> 5, v = tid & 31;
  size_t base = ((size_t)b * 4096 + qx) * 256 + h * 32 + v;
  for (int qy = 0; qy < 64; ++qy) {
    float acc = 0.f;
#pragma unroll
    for (int ky = 0; ky < 32; ++ky) acc += AyL[qy][ky] * t[ky];
    float o = gelu_f(acc * invSx / Sy[qy]);
    unsigned short hi, lo;
    split_bf(o, hi, lo);
    size_t idx = base + (size_t)qy * 64 * 256;
    ohi[idx] = hi;
    olo[idx] = lo;
  }
}

// ---------------------------------------------------------------------------
__global__ __launch_bounds__(256) void k_fc2(const float* __restrict__ h,
                                             const float* __restrict__ w,
                                             const float* __restrict__ b,
                                             float* __restrict__ out) {
  int row = blockIdx.x * 4 + (threadIdx.x >> 6);
  int lane = threadIdx.x & 63;
  float4 hv = *(const float4*)(h + (size_t)row * 256 + lane * 4);
  float4 wv = *(const float4*)(w + lane * 4);
  float s = hv.x * wv.x + hv.y * wv.y + hv.z * wv.z + hv.w * wv.w;
#pragma unroll
  for (int off = 32; off > 0; off >>= 1) s += __shfl_down(s, off, 64);
  if (lane == 0) out[row] = s + b[0];
}

// ---------------------------------------------------------------------------
extern "C" void kernel_launch(void* const* d_in, const int* in_sizes, int n_in,
                              void* d_out, int out_size, void* d_ws,
                              size_t ws_size, hipStream_t stream) {
  const float* x      = (const float*)d_in[0];
  const float* en_w   = (const float*)d_in[1];
  const float* en_b   = (const float*)d_in[2];
  const float* down_r = (const float*)d_in[3];
  const float* down_w = (const float*)d_in[4];
  const float* pa_r   = (const float*)d_in[5];
  const float* pa_w   = (const float*)d_in[6];
  const float* mlp1_w = (const float*)d_in[7];
  const float* mlp1_b = (const float*)d_in[8];
  const float* mlp2_w = (const float*)d_in[9];
  const float* mlp2_b = (const float*)d_in[10];
  const float* res_w  = (const float*)d_in[11];
  const float* res_b  = (const float*)d_in[12];
  const float* up_r   = (const float*)d_in[13];
  const float* up_w   = (const float*)d_in[14];
  const float* de1_w  = (const float*)d_in[15];
  const float* de1_b  = (const float*)d_in[16];
  const float* de2_w  = (const float*)d_in[17];
  const float* de2_b  = (const float*)d_in[18];
  float* out = (float*)d_out;

  constexpr int JMAX = 144;
  float* ws = (float*)d_ws;
  // A region repurposed: bf16 hi/lo of the 32768x256 activations.
  unsigned short* Ahi = (unsigned short*)ws;       // 8388608 ushorts
  unsigned short* Alo = Ahi + 8388608;             // ends at float offset 8388608
  float* B = ws + 8388608;        // [h][4096][bv] value_down; T; dec hidden
  float* lat0 = B + 8388608;      // h in/out of processor iters
  float* lat1 = lat0 + 2097152;   // value / mlp1-out
  float* lat2 = lat1 + 2097152;   // res_pre
  float* lat3 = lat2 + 2097152;   // pa_out
  float* wlD = lat3 + 2097152;    // [8,1024,JMAX]
  float* wlP = wlD + 8 * 1024 * JMAX;
  int* thrD = (int*)(wlP + 8 * 1024 * JMAX);
  int* thrP = thrD + 1024;
  int* cntD = thrP + 1024;
  int* cntP = cntD + 1024;
  int* klD = cntP + 1024;         // [1024,JMAX]
  int* klP = klD + 1024 * JMAX;
  unsigned short* WhiD = (unsigned short*)(klP + 1024 * JMAX);  // down_w [n][k]
  unsigned short* WloD = WhiD + 65536;
  unsigned short* Whi1 = WloD + 65536;  // de1_w [n][k]
  unsigned short* Wlo1 = Whi1 + 65536;

  // 1. encoder -> bf16 hi/lo
  k_enc<<<32768, 256, 0, stream>>>(x, en_w, en_b, Ahi, Alo);
  // 2. weight splits + thresholds + key lists (input-independent, tiny)
  k_split_wv<<<256, 256, 0, stream>>>(down_w, WhiD, WloD);
  k_split_w<<<256, 256, 0, stream>>>(de1_w, Whi1, Wlo1);
  k_thresh<64, 2, 16, 82, 7938><<<1024, 256, 0, stream>>>(thrD);
  k_thresh<32, 1, 4, 103, 1922><<<1024, 256, 0, stream>>>(thrP);
  k_klist<64, 2, 13, JMAX><<<1024, 256, 0, stream>>>(down_r, thrD, klD, cntD, wlD);
  k_klist<32, 1, 11, JMAX><<<1024, 256, 0, stream>>>(pa_r, thrP, klP, cntP, wlP);
  // 3. down: value via split-bf16 MFMA, then per-(q,h) sparse attention
  k_mfma<1, false><<<dim3(256, 2), 256, 0, stream>>>(Ahi, Alo, WhiD, WloD,
                                                     nullptr, B);
  k_att2h<4096, JMAX><<<8192, 256, 0, stream>>>(B, klD, cntD, wlD, lat0);
  // 4. processor blocks (fp32 GEMMs)
  for (int i = 0; i < 4; ++i) {
    k_value_res<<<dim3(128, 8), 256, 0, stream>>>(
        lat0, pa_w + (size_t)i * 65536, res_w + (size_t)i * 65536, lat1, lat2);
    k_att2h<1024, JMAX><<<8192, 256, 0, stream>>>(lat1, klP, cntP, wlP, lat3);
    k_gemm<0, 0, true, false><<<dim3(128, 4), 256, 0, stream>>>(
        lat3, mlp1_w + (size_t)i * 65536, mlp1_b + i * 256, nullptr, nullptr,
        lat1, 0);
    k_gemm<0, 0, true, true><<<dim3(128, 4), 256, 0, stream>>>(
        lat1, mlp2_w + (size_t)i * 65536, mlp2_b + i * 256, res_b + i * 256,
        lat2, lat0, 0);
  }
  // 5. up: value then separable attention; s2 emits bf16 hi/lo
  k_gemm<1, 1, false, false><<<dim3(128, 4), 256, 0, stream>>>(
      lat0, up_w, nullptr, nullptr, nullptr, lat1, 10);
  k_up_s1<<<dim3(32, 8), 256, 0, stream>>>(lat1, up_r, B);
  k_up_s2<<<dim3(64, 8), 256, 0, stream>>>(B, up_r, Ahi, Alo);
  // 6. decoder: fc1 via split-bf16 MFMA, then fc2
  k_mfma<0, true><<<dim3(256, 2), 256, 0, stream>>>(Ahi, Alo, Whi1, Wlo1,
                                                    de1_b, B);
  k_fc2<<<8192, 256, 0, stream>>>(B, de2_w, de2_b, out);
}

// Round 7
// 694.413 us; speedup vs baseline: 2.5424x; 1.2178x over previous
//
#include <hip/hip_runtime.h>
#include <math.h>

// ---------------------------------------------------------------------------
// PiTWithCoords: position-attention transformer on fixed grids.
//  * m_dist EXACT in fp32: d_int / 2^S (down S=13, proc S=11, up S=13).
//  * percentile mask == integer threshold on d_int (order statistic).
//  * att weights input/batch-independent; down/proc = sparse gather with
//    precomputed normalized weights; h=blockIdx%8 XCD-locality split.
//  * UP attention separable (Kronecker): O = Ay*(Ax*V), den = Sx*Sy.
//  * R6: ALL GEMMs split-bf16 MFMA (a=hi+lo, 3x mfma_f32_16x16x32_bf16);
//    activations flow as bf16 hi/lo pairs; mlp2+res = dual-A K=512 MFMA;
//    k_thresh atomic -> shuffle reduction (was 50us of LDS-atomic serial).
// ---------------------------------------------------------------------------

#define PI_F 3.14159265358979323846f

typedef __attribute__((ext_vector_type(8))) short short8;
typedef __attribute__((ext_vector_type(4))) float float4v;

__device__ __forceinline__ float gelu_f(float x) {
  float u = 0.7978845608028654f * (x + 0.044715f * x * x * x);
  float e = __expf(2.0f * u);
  float t = 1.0f - 2.0f / (e + 1.0f);
  return 0.5f * x * (1.0f + t);
}

__device__ __forceinline__ float head_scale(float r) {
  return tanf(0.25f * PI_F * (1.0f - 1e-7f) * (1.0f + sinf(r)));
}

__device__ __forceinline__ unsigned short f2bf(float f) {
  union { float f; unsigned u; } c; c.f = f;
  unsigned u = c.u + 0x7FFFu + ((c.u >> 16) & 1u);
  return (unsigned short)(u >> 16);
}
__device__ __forceinline__ float bf2f(unsigned short h) {
  union { unsigned u; float f; } c; c.u = ((unsigned)h) << 16;
  return c.f;
}
__device__ __forceinline__ void split_bf(float f, unsigned short& hi,
                                         unsigned short& lo) {
  hi = f2bf(f);
  lo = f2bf(f - bf2f(hi));
}

// ---------------------------------------------------------------------------
// Encoder -> bf16 hi/lo activations.
// ---------------------------------------------------------------------------
__global__ __launch_bounds__(256) void k_enc(
    const float* __restrict__ x, const float* __restrict__ w,
    const float* __restrict__ b, unsigned short* __restrict__ ahi,
    unsigned short* __restrict__ alo) {
  int row = blockIdx.x;
  int o = threadIdx.x;
  float4 xv = *(const float4*)(x + (size_t)row * 4);
  float4 wv = *(const float4*)(w + (size_t)o * 4);
  float s = xv.x * wv.x + xv.y * wv.y + xv.z * wv.z + xv.w * wv.w + b[o];
  s = gelu_f(s);
  unsigned short hi, lo;
  split_bf(s, hi, lo);
  ahi[(size_t)row * 256 + o] = hi;
  alo[(size_t)row * 256 + o] = lo;
}

// ---------------------------------------------------------------------------
// One-shot weight splitter. dst layout [n][k] ushort hi/lo, segments:
//  down@0(64K) de1@65536 up@131072 pa@196608(4x64K) mlp1@458752 mlp2@720896
//  res@983040; total 1245184 elems. grid 4864 x 256.
// ---------------------------------------------------------------------------
__global__ __launch_bounds__(256) void k_split_all(
    const float* __restrict__ down_w, const float* __restrict__ de1_w,
    const float* __restrict__ up_w, const float* __restrict__ pa_w,
    const float* __restrict__ mlp1_w, const float* __restrict__ mlp2_w,
    const float* __restrict__ res_w, unsigned short* __restrict__ whi,
    unsigned short* __restrict__ wlo) {
  int i = blockIdx.x * 256 + threadIdx.x;
  float f;
  if (i < 65536) {
    int n = i >> 8, k = i & 255;
    f = down_w[(n >> 5) * 8192 + k * 32 + (n & 31)];
  } else if (i < 131072) {
    f = de1_w[i - 65536];
  } else if (i < 196608) {
    int j = i - 131072;
    int n = j >> 8, k = j & 255;
    f = up_w[(n >> 5) * 8192 + k * 32 + (n & 31)];
  } else if (i < 458752) {
    int j = i - 196608;
    int blk = j >> 16, r = j & 65535;
    int n = r >> 8, k = r & 255;
    f = pa_w[(size_t)blk * 65536 + (n >> 5) * 8192 + k * 32 + (n & 31)];
  } else if (i < 720896) {
    f = mlp1_w[i - 458752];
  } else if (i < 983040) {
    f = mlp2_w[i - 720896];
  } else {
    f = res_w[i - 983040];
  }
  unsigned short hi, lo;
  split_bf(f, hi, lo);
  whi[i] = hi;
  wlo[i] = lo;
}

// ---------------------------------------------------------------------------
// Order-statistic threshold; shuffle-reduced count (no LDS atomics).
// ---------------------------------------------------------------------------
template <int KRES, int CXM, int NPT, int TARGET, int TMAX>
__global__ __launch_bounds__(256) void k_thresh(int* __restrict__ thr) {
  __shared__ int wsum[4];
  int q = blockIdx.x, tid = threadIdx.x;
  int qx = q & 31, qy = q >> 5;
  int cx = qx * CXM, cy = qy * CXM;
  int d[NPT];
#pragma unroll
  for (int j = 0; j < NPT; ++j) {
    int k = tid * NPT + j;
    int kx = k & (KRES - 1), ky = k / KRES;
    int dx = cx - kx, dy = cy - ky;
    d[j] = dx * dx + dy * dy;
  }
  int lo = 0, hi = TMAX;
  while (lo < hi) {
    int mid = (lo + hi) >> 1;
    int c = 0;
#pragma unroll
    for (int j = 0; j < NPT; ++j) c += (d[j] <= mid) ? 1 : 0;
#pragma unroll
    for (int off = 32; off > 0; off >>= 1) c += __shfl_down(c, off, 64);
    if ((tid & 63) == 0) wsum[tid >> 6] = c;
    __syncthreads();
    int total = wsum[0] + wsum[1] + wsum[2] + wsum[3];
    __syncthreads();
    if (total >= TARGET) hi = mid; else lo = mid + 1;
  }
  if (tid == 0) thr[q] = lo;
}

// ---------------------------------------------------------------------------
// Compacted key list + normalized per-(h,q) weights.
// ---------------------------------------------------------------------------
template <int KRES, int CXM, int DSHIFT, int JMAX>
__global__ __launch_bounds__(256) void k_klist(
    const float* __restrict__ rvec, const int* __restrict__ thr,
    int* __restrict__ klist, int* __restrict__ kcnt,
    float* __restrict__ wlist) {
  __shared__ int cntS;
  __shared__ int sidx[JMAX];
  __shared__ int sdv[JMAX];
  __shared__ float wbuf[8][JMAX];
  __shared__ float denS[8];
  int q = blockIdx.x, tid = threadIdx.x;
  int qx = q & 31, qy = q >> 5;
  int cx = qx * CXM, cy = qy * CXM;
  int T = thr[q];
  if (tid == 0) cntS = 0;
  __syncthreads();
  int rad = (int)sqrtf((float)T);
  while ((rad + 1) * (rad + 1) <= T) ++rad;
  while (rad > 0 && rad * rad > T) --rad;
  int x0 = max(0, cx - rad), x1 = min(KRES - 1, cx + rad);
  int y0 = max(0, cy - rad), y1 = min(KRES - 1, cy + rad);
  int W = x1 - x0 + 1, H = y1 - y0 + 1, tot = W * H;
  for (int p = tid; p < tot; p += 256) {
    int kx = x0 + p % W, ky = y0 + p / W;
    int dx = cx - kx, dy = cy - ky;
    int d = dx * dx + dy * dy;
    if (d <= T) {
      int s = atomicAdd(&cntS, 1);
      if (s < JMAX) { sidx[s] = ky * KRES + kx; sdv[s] = d; }
    }
  }
  __syncthreads();
  int cnt = min(cntS, JMAX);
  int h = tid >> 5, j0 = tid & 31;
  float sc = head_scale(rvec[h]) * (1.0f / (float)(1 << DSHIFT));
  float ds = 0.f;
  for (int j = j0; j < cnt; j += 32) {
    float w = __expf(-sc * (float)sdv[j]);
    wbuf[h][j] = w;
    ds += w;
  }
#pragma unroll
  for (int off = 16; off > 0; off >>= 1) ds += __shfl_down(ds, off, 32);
  if (j0 == 0) denS[h] = ds;
  __syncthreads();
  float inv = 1.0f / denS[h];
  for (int j = j0; j < cnt; j += 32)
    wlist[((size_t)h * 1024 + q) * JMAX + j] = wbuf[h][j] * inv;
  if (tid == 0) kcnt[q] = cnt;
  if (h == 0)
    for (int j = j0; j < cnt; j += 32) klist[(size_t)q * JMAX + j] = sidx[j];
}

// ---------------------------------------------------------------------------
// Unified split-bf16 MFMA GEMM. A [M,256] hi/lo, W [n][k] hi/lo.
// Tile 128x128, 4 waves = 2x2 of 64x64, BK=32. DUAL: K=512 (A2*W2 appended).
// Epilogue: +bias (+bias2); GEL; then
//   OHILO: store hi/lo ushort [m*256+n]
//   else OL=0: fp32 [m*256+n];  OL=1: value layout, N=1<<NS:
//     out[(((n>>5)*N + (m&(N-1)))*8 + (m>>NS))*32 + (n&31)].
// ---------------------------------------------------------------------------
template <bool DUAL, int OL, bool GEL, bool OHILO>
__global__ __launch_bounds__(256) void k_mf(
    const unsigned short* __restrict__ A1hi, const unsigned short* __restrict__ A1lo,
    const unsigned short* __restrict__ W1hi, const unsigned short* __restrict__ W1lo,
    const unsigned short* __restrict__ A2hi, const unsigned short* __restrict__ A2lo,
    const unsigned short* __restrict__ W2hi, const unsigned short* __restrict__ W2lo,
    const float* __restrict__ bias, const float* __restrict__ bias2,
    float* __restrict__ outf, unsigned short* __restrict__ ohi,
    unsigned short* __restrict__ olo, int NS) {
  __shared__ unsigned short Ah[128][40], Al[128][40];
  __shared__ unsigned short Bh[128][40], Bl[128][40];
  int tid = threadIdx.x;
  int m0 = blockIdx.x * 128, n0 = blockIdx.y * 128;
  int w = tid >> 6, lane = tid & 63;
  int wm = (w >> 1) * 64, wn = (w & 1) * 64;
  int quad = lane >> 4, l16 = lane & 15;
  float4v acc[4][4];
#pragma unroll
  for (int i = 0; i < 4; ++i)
#pragma unroll
    for (int j = 0; j < 4; ++j) acc[i][j] = (float4v)0.0f;

  int srow = tid >> 1, skq = (tid & 1) * 16;
  const int KT = DUAL ? 512 : 256;
  for (int kk = 0; kk < KT; kk += 32) {
    const unsigned short *pAh, *pAl, *pWh, *pWl;
    int kb;
    if (DUAL && kk >= 256) {
      pAh = A2hi; pAl = A2lo; pWh = W2hi; pWl = W2lo; kb = kk - 256;
    } else {
      pAh = A1hi; pAl = A1lo; pWh = W1hi; pWl = W1lo; kb = kk;
    }
    {
      size_t ga = (size_t)(m0 + srow) * 256 + kb + skq;
      const uint4* pah = (const uint4*)(pAh + ga);
      const uint4* pal = (const uint4*)(pAl + ga);
      *(uint4*)&Ah[srow][skq] = pah[0];
      *(uint4*)&Ah[srow][skq + 8] = pah[1];
      *(uint4*)&Al[srow][skq] = pal[0];
      *(uint4*)&Al[srow][skq + 8] = pal[1];
      size_t gb = (size_t)(n0 + srow) * 256 + kb + skq;
      const uint4* pbh = (const uint4*)(pWh + gb);
      const uint4* pbl = (const uint4*)(pWl + gb);
      *(uint4*)&Bh[srow][skq] = pbh[0];
      *(uint4*)&Bh[srow][skq + 8] = pbh[1];
      *(uint4*)&Bl[srow][skq] = pbl[0];
      *(uint4*)&Bl[srow][skq + 8] = pbl[1];
    }
    __syncthreads();
    short8 ah[4], al[4], bh[4], bl[4];
#pragma unroll
    for (int s = 0; s < 4; ++s) {
      ah[s] = *(const short8*)&Ah[wm + s * 16 + l16][quad * 8];
      al[s] = *(const short8*)&Al[wm + s * 16 + l16][quad * 8];
      bh[s] = *(const short8*)&Bh[wn + s * 16 + l16][quad * 8];
      bl[s] = *(const short8*)&Bl[wn + s * 16 + l16][quad * 8];
    }
#pragma unroll
    for (int ms = 0; ms < 4; ++ms)
#pragma unroll
      for (int ns = 0; ns < 4; ++ns) {
        acc[ms][ns] = __builtin_amdgcn_mfma_f32_16x16x32_bf16(
            ah[ms], bh[ns], acc[ms][ns], 0, 0, 0);
        acc[ms][ns] = __builtin_amdgcn_mfma_f32_16x16x32_bf16(
            ah[ms], bl[ns], acc[ms][ns], 0, 0, 0);
        acc[ms][ns] = __builtin_amdgcn_mfma_f32_16x16x32_bf16(
            al[ms], bh[ns], acc[ms][ns], 0, 0, 0);
      }
    __syncthreads();
  }
#pragma unroll
  for (int ms = 0; ms < 4; ++ms) {
#pragma unroll
    for (int ns = 0; ns < 4; ++ns) {
      int n = n0 + wn + ns * 16 + l16;
      float bv = bias ? bias[n] : 0.0f;
      if (DUAL && bias2) bv += bias2[n];
#pragma unroll
      for (int r = 0; r < 4; ++r) {
        int m = m0 + wm + ms * 16 + quad * 4 + r;
        float c = acc[ms][ns][r] + bv;
        if (GEL) c = gelu_f(c);
        if (OHILO) {
          unsigned short chi, clo;
          split_bf(c, chi, clo);
          ohi[(size_t)m * 256 + n] = chi;
          olo[(size_t)m * 256 + n] = clo;
        } else if (OL == 0) {
          outf[(size_t)m * 256 + n] = c;
        } else {
          int N = 1 << NS;
          int bb = m >> NS, rr = m & (N - 1);
          outf[(((size_t)(n >> 5) * N + rr) * 8 + bb) * 32 + (n & 31)] = c;
        }
      }
    }
  }
}

// ---------------------------------------------------------------------------
// Sparse attention, block per (q,h), h = blockIdx%8 (XCD locality).
// Output: bf16 hi/lo activation pairs (feeds MFMA GEMMs).
// ---------------------------------------------------------------------------
template <int NK, int JMAX>
__global__ __launch_bounds__(256) void k_att2h(
    const float* __restrict__ value,   // [h][NK][b*32+v]
    const int* __restrict__ klist, const int* __restrict__ kcnt,
    const float* __restrict__ wlist, unsigned short* __restrict__ ohi,
    unsigned short* __restrict__ olo) {
  __shared__ int kls[JMAX];
  __shared__ float wls[JMAX];
  int blk = blockIdx.x;
  int h = blk & 7, q = blk >> 3;
  int tid = threadIdx.x;
  int cnt = kcnt[q];
  for (int i = tid; i < cnt; i += 256) {
    kls[i] = klist[(size_t)q * JMAX + i];
    wls[i] = wlist[((size_t)h * 1024 + q) * JMAX + i];
  }
  __syncthreads();
  const float* vb = value + (size_t)h * NK * 256 + tid;
  float a0 = 0.f, a1 = 0.f, a2 = 0.f, a3 = 0.f;
  int j = 0;
  for (; j + 4 <= cnt; j += 4) {
    float v0 = vb[(size_t)kls[j + 0] * 256];
    float v1 = vb[(size_t)kls[j + 1] * 256];
    float v2 = vb[(size_t)kls[j + 2] * 256];
    float v3 = vb[(size_t)kls[j + 3] * 256];
    a0 += wls[j + 0] * v0;
    a1 += wls[j + 1] * v1;
    a2 += wls[j + 2] * v2;
    a3 += wls[j + 3] * v3;
  }
  for (; j < cnt; ++j) a0 += wls[j] * vb[(size_t)kls[j] * 256];
  float acc = gelu_f((a0 + a1) + (a2 + a3));
  int b = tid >> 5, v = tid & 31;
  size_t oi = ((size_t)b * 1024 + q) * 256 + h * 32 + v;
  unsigned short hi, lo;
  split_bf(acc, hi, lo);
  ohi[oi] = hi;
  olo[oi] = lo;
}

// ---------------------------------------------------------------------------
// Separable up-attention stage 1: T[h][qx][ky][bv] = sum_kx Ax[qx][kx]*V.
// ---------------------------------------------------------------------------
__global__ __launch_bounds__(256) void k_up_s1(
    const float* __restrict__ value,  // [h][1024][bv]
    const float* __restrict__ rvec, float* __restrict__ T) {
  __shared__ float AxL[64][33];
  int ky = blockIdx.x, h = blockIdx.y, tid = threadIdx.x;
  float sc = head_scale(rvec[h]) * (1.0f / 8192.0f);
  float v[32];
  const float* vb = value + ((size_t)h * 1024 + ky * 32) * 256 + tid;
#pragma unroll
  for (int kx = 0; kx < 32; ++kx) v[kx] = vb[kx * 256];
  if (tid < 64) {
    int qx = tid, dxmin = qx & 1;
    for (int kx = 0; kx < 32; ++kx) {
      int dx = qx - 2 * kx;
      AxL[qx][kx] = __expf(-sc * (float)(dx * dx - dxmin));
    }
  }
  __syncthreads();
  float* tb = T + (((size_t)h * 64) * 32 + ky) * 256 + tid;
  for (int qx = 0; qx < 64; ++qx) {
    float acc = 0.f;
#pragma unroll
    for (int kx = 0; kx < 32; ++kx) acc += AxL[qx][kx] * v[kx];
    tb[(size_t)qx * 32 * 256] = acc;
  }
}

// ---------------------------------------------------------------------------
// Separable up-attention stage 2 -> bf16 hi/lo (feeds dec-fc1 MFMA).
// ---------------------------------------------------------------------------
__global__ __launch_bounds__(256) void k_up_s2(
    const float* __restrict__ T, const float* __restrict__ rvec,
    unsigned short* __restrict__ ohi, unsigned short* __restrict__ olo) {
  __shared__ float AyL[64][33];
  __shared__ float Sy[64];
  __shared__ float SxS;
  int qx = blockIdx.x, h = blockIdx.y, tid = threadIdx.x;
  float sc = head_scale(rvec[h]) * (1.0f / 8192.0f);
  float t[32];
  const float* tb = T + ((size_t)h * 64 + qx) * 32 * 256 + tid;
#pragma unroll
  for (int ky = 0; ky < 32; ++ky) t[ky] = tb[ky * 256];
  if (tid < 64) {
    int qy = tid, dymin = qy & 1;
    float s = 0.f;
    for (int ky = 0; ky < 32; ++ky) {
      int dy = qy - 2 * ky;
      float e = __expf(-sc * (float)(dy * dy - dymin));
      AyL[qy][ky] = e;
      s += e;
    }
    Sy[qy] = s;
  } else if (tid >= 64 && tid < 96) {
    int kx = tid - 64, dxmin = qx & 1;
    int dx = qx - 2 * kx;
    float e = __expf(-sc * (float)(dx * dx - dxmin));
#pragma unroll
    for (int off = 16; off > 0; off >>= 1) e += __shfl_down(e, off, 32);
    if (kx == 0) SxS = e;
  }
  __syncthreads();
  float invSx = 1.0f / SxS;
  int b = tid >> 5, v = tid & 31;
  size_t base = ((size_t)b * 4096 + qx) * 256 + h * 32 + v;
  for (int qy = 0; qy < 64; ++qy) {
    float acc = 0.f;
#pragma unroll
    for (int ky = 0; ky < 32; ++ky) acc += AyL[qy][ky] * t[ky];
    float o = gelu_f(acc * invSx / Sy[qy]);
    unsigned short hi, lo;
    split_bf(o, hi, lo);
    size_t idx = base + (size_t)qy * 64 * 256;
    ohi[idx] = hi;
    olo[idx] = lo;
  }
}

// ---------------------------------------------------------------------------
__global__ __launch_bounds__(256) void k_fc2(const float* __restrict__ h,
                                             const float* __restrict__ w,
                                             const float* __restrict__ b,
                                             float* __restrict__ out) {
  int row = blockIdx.x * 4 + (threadIdx.x >> 6);
  int lane = threadIdx.x & 63;
  float4 hv = *(const float4*)(h + (size_t)row * 256 + lane * 4);
  float4 wv = *(const float4*)(w + lane * 4);
  float s = hv.x * wv.x + hv.y * wv.y + hv.z * wv.z + hv.w * wv.w;
#pragma unroll
  for (int off = 32; off > 0; off >>= 1) s += __shfl_down(s, off, 64);
  if (lane == 0) out[row] = s + b[0];
}

// ---------------------------------------------------------------------------
extern "C" void kernel_launch(void* const* d_in, const int* in_sizes, int n_in,
                              void* d_out, int out_size, void* d_ws,
                              size_t ws_size, hipStream_t stream) {
  const float* x      = (const float*)d_in[0];
  const float* en_w   = (const float*)d_in[1];
  const float* en_b   = (const float*)d_in[2];
  const float* down_r = (const float*)d_in[3];
  const float* down_w = (const float*)d_in[4];
  const float* pa_r   = (const float*)d_in[5];
  const float* pa_w   = (const float*)d_in[6];
  const float* mlp1_w = (const float*)d_in[7];
  const float* mlp1_b = (const float*)d_in[8];
  const float* mlp2_w = (const float*)d_in[9];
  const float* mlp2_b = (const float*)d_in[10];
  const float* res_w  = (const float*)d_in[11];
  const float* res_b  = (const float*)d_in[12];
  const float* up_r   = (const float*)d_in[13];
  const float* up_w   = (const float*)d_in[14];
  const float* de1_w  = (const float*)d_in[15];
  const float* de1_b  = (const float*)d_in[16];
  const float* de2_w  = (const float*)d_in[17];
  const float* de2_b  = (const float*)d_in[18];
  float* out = (float*)d_out;

  constexpr int JMAX = 144;
  float* ws = (float*)d_ws;
  // [0, 8388608): enc / up_s2 activations, bf16 hi/lo (32768x256 each)
  unsigned short* Ahi = (unsigned short*)ws;
  unsigned short* Alo = Ahi + 8388608;
  // [8388608, 16777216): B fp32 — down value / proc+up value / T / dec hidden
  float* B = ws + 8388608;
  float* Tbuf = B + 2097152;  // T for up stage (inside B region)
  // [16777216, 25165824): activation hi/lo pairs (each 2097152 ushorts)
  unsigned short* hAhi = (unsigned short*)(ws + 16777216);
  unsigned short* hAlo = hAhi + 2097152;
  unsigned short* hBhi = hAlo + 2097152;
  unsigned short* hBlo = hBhi + 2097152;
  unsigned short* pahi = hBlo + 2097152;
  unsigned short* palo = pahi + 2097152;
  unsigned short* m1hi = palo + 2097152;
  unsigned short* m1lo = m1hi + 2097152;
  // [25165824, ...): wlists, thresholds, key lists, weight splits
  float* wlD = ws + 25165824;          // [8,1024,JMAX]
  float* wlP = wlD + 1179648;
  int* thrD = (int*)(wlP + 1179648);
  int* thrP = thrD + 1024;
  int* cntD = thrP + 1024;
  int* cntP = cntD + 1024;
  int* klD = cntP + 1024;              // [1024,JMAX]
  int* klP = klD + 147456;
  unsigned short* Whi = (unsigned short*)(klP + 147456);  // 1245184 each
  unsigned short* Wlo = Whi + 1245184;
  const int WO_DOWN = 0, WO_DE1 = 65536, WO_UP = 131072, WO_PA = 196608,
            WO_MLP1 = 458752, WO_MLP2 = 720896, WO_RES = 983040;

  // 1. encoder -> bf16 hi/lo
  k_enc<<<32768, 256, 0, stream>>>(x, en_w, en_b, Ahi, Alo);
  // 2. weight splits + thresholds + key lists (input-independent)
  k_split_all<<<4864, 256, 0, stream>>>(down_w, de1_w, up_w, pa_w, mlp1_w,
                                        mlp2_w, res_w, Whi, Wlo);
  k_thresh<64, 2, 16, 82, 7938><<<1024, 256, 0, stream>>>(thrD);
  k_thresh<32, 1, 4, 103, 1922><<<1024, 256, 0, stream>>>(thrP);
  k_klist<64, 2, 13, JMAX><<<1024, 256, 0, stream>>>(down_r, thrD, klD, cntD, wlD);
  k_klist<32, 1, 11, JMAX><<<1024, 256, 0, stream>>>(pa_r, thrP, klP, cntP, wlP);
  // 3. down: value MFMA -> B [h][4096][bv]; sparse att -> hA (hi/lo)
  k_mf<false, 1, false, false><<<dim3(256, 2), 256, 0, stream>>>(
      Ahi, Alo, Whi + WO_DOWN, Wlo + WO_DOWN, nullptr, nullptr, nullptr,
      nullptr, nullptr, nullptr, B, nullptr, nullptr, 12);
  k_att2h<4096, JMAX><<<8192, 256, 0, stream>>>(B, klD, cntD, wlD, hAhi, hAlo);
  // 4. processor blocks, h ping-pong hA <-> hB (all split-bf16 MFMA)
  for (int i = 0; i < 4; ++i) {
    const unsigned short* hih = (i & 1) ? hBhi : hAhi;
    const unsigned short* hil = (i & 1) ? hBlo : hAlo;
    unsigned short* hoh = (i & 1) ? hAhi : hBhi;
    unsigned short* hol = (i & 1) ? hAlo : hBlo;
    // value = h * pa_w_i -> B [h][1024][bv]
    k_mf<false, 1, false, false><<<dim3(64, 2), 256, 0, stream>>>(
        hih, hil, Whi + WO_PA + i * 65536, Wlo + WO_PA + i * 65536, nullptr,
        nullptr, nullptr, nullptr, nullptr, nullptr, B, nullptr, nullptr, 10);
    // pa_out = sparse attention (hi/lo)
    k_att2h<1024, JMAX><<<8192, 256, 0, stream>>>(B, klP, cntP, wlP, pahi, palo);
    // m1 = gelu(pa_out * mlp1 + b1) (hi/lo)
    k_mf<false, 0, true, true><<<dim3(64, 2), 256, 0, stream>>>(
        pahi, palo, Whi + WO_MLP1 + i * 65536, Wlo + WO_MLP1 + i * 65536,
        nullptr, nullptr, nullptr, nullptr, mlp1_b + i * 256, nullptr, nullptr,
        m1hi, m1lo, 0);
    // h' = gelu(m1*mlp2 + h*res + b2 + br) (dual, hi/lo)
    k_mf<true, 0, true, true><<<dim3(64, 2), 256, 0, stream>>>(
        m1hi, m1lo, Whi + WO_MLP2 + i * 65536, Wlo + WO_MLP2 + i * 65536, hih,
        hil, Whi + WO_RES + i * 65536, Wlo + WO_RES + i * 65536,
        mlp2_b + i * 256, res_b + i * 256, nullptr, hoh, hol, 0);
  }
  // 5. up: value MFMA -> B[0..2M) [h][1024][bv]; separable attention
  k_mf<false, 1, false, false><<<dim3(64, 2), 256, 0, stream>>>(
      hAhi, hAlo, Whi + WO_UP, Wlo + WO_UP, nullptr, nullptr, nullptr, nullptr,
      nullptr, nullptr, B, nullptr, nullptr, 10);
  k_up_s1<<<dim3(32, 8), 256, 0, stream>>>(B, up_r, Tbuf);
  k_up_s2<<<dim3(64, 8), 256, 0, stream>>>(Tbuf, up_r, Ahi, Alo);
  // 6. decoder: fc1 MFMA -> B fp32; fc2 reduction
  k_mf<false, 0, true, false><<<dim3(256, 2), 256, 0, stream>>>(
      Ahi, Alo, Whi + WO_DE1, Wlo + WO_DE1, nullptr, nullptr, nullptr, nullptr,
      de1_b, nullptr, B, nullptr, nullptr, 0);
  k_fc2<<<8192, 256, 0, stream>>>(B, de2_w, de2_b, out);
}

// Round 9
// 482.269 us; speedup vs baseline: 3.6608x; 1.4399x over previous
//
#include <hip/hip_runtime.h>
#include <math.h>

// ---------------------------------------------------------------------------
// PiTWithCoords: position-attention transformer on fixed grids.
//  * m_dist EXACT in fp32: d_int / 2^S (down S=13, proc S=11, up S=13).
//  * percentile mask == integer threshold on d_int (order statistic).
//  * att weights input/batch-independent; down/proc = sparse gather with
//    precomputed normalized weights; h in low block bits (XCD locality).
//  * UP attention separable (Kronecker): O = Ay*(Ax*V), den = Sx*Sy.
//  * All GEMMs split-bf16 MFMA (a=hi+lo, 3x mfma_f32_16x16x32_bf16).
//  * R8 fix: R7 crashed because the misc region (klists/weights) aliased
//    the pa/m1 activation buffers -> clobbered key lists -> OOB gather.
//    Misc region now starts AFTER all activation pairs (offset 25165824).
// ---------------------------------------------------------------------------

#define PI_F 3.14159265358979323846f

typedef __attribute__((ext_vector_type(8))) short short8;
typedef __attribute__((ext_vector_type(4))) float float4v;
typedef __attribute__((ext_vector_type(4))) unsigned short ushort4v;

__device__ __forceinline__ float gelu_f(float x) {
  float u = 0.7978845608028654f * (x + 0.044715f * x * x * x);
  float e = __expf(2.0f * u);
  float t = 1.0f - 2.0f / (e + 1.0f);
  return 0.5f * x * (1.0f + t);
}

__device__ __forceinline__ float head_scale(float r) {
  return tanf(0.25f * PI_F * (1.0f - 1e-7f) * (1.0f + sinf(r)));
}

__device__ __forceinline__ unsigned short f2bf(float f) {
  union { float f; unsigned u; } c; c.f = f;
  unsigned u = c.u + 0x7FFFu + ((c.u >> 16) & 1u);
  return (unsigned short)(u >> 16);
}
__device__ __forceinline__ float bf2f(unsigned short h) {
  union { unsigned u; float f; } c; c.u = ((unsigned)h) << 16;
  return c.f;
}
__device__ __forceinline__ void split_bf(float f, unsigned short& hi,
                                         unsigned short& lo) {
  hi = f2bf(f);
  lo = f2bf(f - bf2f(hi));
}

// ---------------------------------------------------------------------------
// Encoder -> bf16 hi/lo activations.
// ---------------------------------------------------------------------------
__global__ __launch_bounds__(256) void k_enc(
    const float* __restrict__ x, const float* __restrict__ w,
    const float* __restrict__ b, unsigned short* __restrict__ ahi,
    unsigned short* __restrict__ alo) {
  int row = blockIdx.x;
  int o = threadIdx.x;
  float4 xv = *(const float4*)(x + (size_t)row * 4);
  float4 wv = *(const float4*)(w + (size_t)o * 4);
  float s = xv.x * wv.x + xv.y * wv.y + xv.z * wv.z + xv.w * wv.w + b[o];
  s = gelu_f(s);
  unsigned short hi, lo;
  split_bf(s, hi, lo);
  ahi[(size_t)row * 256 + o] = hi;
  alo[(size_t)row * 256 + o] = lo;
}

// ---------------------------------------------------------------------------
// One-shot weight splitter. dst layout [n][k] ushort hi/lo, segments:
//  down@0(64K) de1@65536 up@131072 pa@196608(4x64K) mlp1@458752 mlp2@720896
//  res@983040; total 1245184 elems. grid 4864 x 256.
// ---------------------------------------------------------------------------
__global__ __launch_bounds__(256) void k_split_all(
    const float* __restrict__ down_w, const float* __restrict__ de1_w,
    const float* __restrict__ up_w, const float* __restrict__ pa_w,
    const float* __restrict__ mlp1_w, const float* __restrict__ mlp2_w,
    const float* __restrict__ res_w, unsigned short* __restrict__ whi,
    unsigned short* __restrict__ wlo) {
  int i = blockIdx.x * 256 + threadIdx.x;
  float f;
  if (i < 65536) {
    int n = i >> 8, k = i & 255;
    f = down_w[(n >> 5) * 8192 + k * 32 + (n & 31)];
  } else if (i < 131072) {
    f = de1_w[i - 65536];
  } else if (i < 196608) {
    int j = i - 131072;
    int n = j >> 8, k = j & 255;
    f = up_w[(n >> 5) * 8192 + k * 32 + (n & 31)];
  } else if (i < 458752) {
    int j = i - 196608;
    int blk = j >> 16, r = j & 65535;
    int n = r >> 8, k = r & 255;
    f = pa_w[(size_t)blk * 65536 + (n >> 5) * 8192 + k * 32 + (n & 31)];
  } else if (i < 720896) {
    f = mlp1_w[i - 458752];
  } else if (i < 983040) {
    f = mlp2_w[i - 720896];
  } else {
    f = res_w[i - 983040];
  }
  unsigned short hi, lo;
  split_bf(f, hi, lo);
  whi[i] = hi;
  wlo[i] = lo;
}

// ---------------------------------------------------------------------------
// Order-statistic threshold; shuffle-reduced count.
// ---------------------------------------------------------------------------
template <int KRES, int CXM, int NPT, int TARGET, int TMAX>
__global__ __launch_bounds__(256) void k_thresh(int* __restrict__ thr) {
  __shared__ int wsum[4];
  int q = blockIdx.x, tid = threadIdx.x;
  int qx = q & 31, qy = q >> 5;
  int cx = qx * CXM, cy = qy * CXM;
  int d[NPT];
#pragma unroll
  for (int j = 0; j < NPT; ++j) {
    int k = tid * NPT + j;
    int kx = k & (KRES - 1), ky = k / KRES;
    int dx = cx - kx, dy = cy - ky;
    d[j] = dx * dx + dy * dy;
  }
  int lo = 0, hi = TMAX;
  while (lo < hi) {
    int mid = (lo + hi) >> 1;
    int c = 0;
#pragma unroll
    for (int j = 0; j < NPT; ++j) c += (d[j] <= mid) ? 1 : 0;
#pragma unroll
    for (int off = 32; off > 0; off >>= 1) c += __shfl_down(c, off, 64);
    if ((tid & 63) == 0) wsum[tid >> 6] = c;
    __syncthreads();
    int total = wsum[0] + wsum[1] + wsum[2] + wsum[3];
    __syncthreads();
    if (total >= TARGET) hi = mid; else lo = mid + 1;
  }
  if (tid == 0) thr[q] = lo;
}

// ---------------------------------------------------------------------------
// 2x2-q-tile union key list + per-(h,tile,cell) float4 of normalized weights
// (w_i = 0 for cells outside disc i). One block per tile (16x16 tiles).
// ---------------------------------------------------------------------------
template <int KRES, int CXM, int DSHIFT, int J2>
__global__ __launch_bounds__(256) void k_klist2(
    const float* __restrict__ rvec, const int* __restrict__ thr,
    int* __restrict__ klist2, int* __restrict__ kcnt2,
    float* __restrict__ wlist2) {
  __shared__ int cntS;
  __shared__ int sidx[J2];
  __shared__ int sdv[J2][4];
  __shared__ float denS[8][4];
  int tile = blockIdx.x, tid = threadIdx.x;
  int tx = tile & 15, ty = tile >> 4;
  int cxA[4], cyA[4], T[4];
#pragma unroll
  for (int i = 0; i < 4; ++i) {
    int qx = 2 * tx + (i & 1), qy = 2 * ty + (i >> 1);
    cxA[i] = qx * CXM; cyA[i] = qy * CXM;
    T[i] = thr[qy * 32 + qx];
  }
  if (tid == 0) cntS = 0;
  __syncthreads();
  int x0 = KRES - 1, x1 = 0, y0 = KRES - 1, y1 = 0;
#pragma unroll
  for (int i = 0; i < 4; ++i) {
    int rad = (int)sqrtf((float)T[i]);
    while ((rad + 1) * (rad + 1) <= T[i]) ++rad;
    while (rad > 0 && rad * rad > T[i]) --rad;
    x0 = min(x0, max(0, cxA[i] - rad));
    x1 = max(x1, min(KRES - 1, cxA[i] + rad));
    y0 = min(y0, max(0, cyA[i] - rad));
    y1 = max(y1, min(KRES - 1, cyA[i] + rad));
  }
  int W = x1 - x0 + 1, H = y1 - y0 + 1, tot = W * H;
  for (int p = tid; p < tot; p += 256) {
    int kx = x0 + p % W, ky = y0 + p / W;
    int d[4]; bool keep = false;
#pragma unroll
    for (int i = 0; i < 4; ++i) {
      int dx = cxA[i] - kx, dy = cyA[i] - ky;
      d[i] = dx * dx + dy * dy;
      keep = keep || (d[i] <= T[i]);
    }
    if (keep) {
      int s = atomicAdd(&cntS, 1);
      if (s < J2) {
        sidx[s] = ky * KRES + kx;
#pragma unroll
        for (int i = 0; i < 4; ++i) sdv[s][i] = d[i];
      }
    }
  }
  __syncthreads();
  int cnt = min(cntS, J2);
  int h = tid >> 5, lane = tid & 31;
  float sc = head_scale(rvec[h]) * (1.0f / (float)(1 << DSHIFT));
  float den[4] = {0.f, 0.f, 0.f, 0.f};
  for (int j = lane; j < cnt; j += 32) {
#pragma unroll
    for (int i = 0; i < 4; ++i)
      if (sdv[j][i] <= T[i]) den[i] += __expf(-sc * (float)sdv[j][i]);
  }
#pragma unroll
  for (int i = 0; i < 4; ++i) {
    float d0 = den[i];
#pragma unroll
    for (int off = 16; off > 0; off >>= 1) d0 += __shfl_down(d0, off, 32);
    if (lane == 0) denS[h][i] = d0;
  }
  __syncthreads();
  float inv[4];
#pragma unroll
  for (int i = 0; i < 4; ++i) inv[i] = 1.0f / denS[h][i];
  for (int j = lane; j < cnt; j += 32) {
    float w[4];
#pragma unroll
    for (int i = 0; i < 4; ++i)
      w[i] = (sdv[j][i] <= T[i]) ? __expf(-sc * (float)sdv[j][i]) * inv[i] : 0.f;
    float4v wv = {w[0], w[1], w[2], w[3]};
    *(float4v*)&wlist2[(((size_t)h * 256 + tile) * J2 + j) * 4] = wv;
  }
  if (tid == 0) kcnt2[tile] = cnt;
  if (h == 0)
    for (int j = lane; j < cnt; j += 32) klist2[(size_t)tile * J2 + j] = sidx[j];
}

// ---------------------------------------------------------------------------
// Tiled sparse attention: block = (2x2 q-tile, h), h in low bits (XCD).
// g = channel-group (64 x float4), s = j-stride (4). One coalesced 1KB
// float4 row load -> 16 FMA (4 q x 4 ch).
// ---------------------------------------------------------------------------
template <int NK, int J2>
__global__ __launch_bounds__(256) void k_att3(
    const float* __restrict__ value,   // [h][NK][b*32+v]
    const int* __restrict__ klist2, const int* __restrict__ kcnt2,
    const float* __restrict__ wlist2, unsigned short* __restrict__ ohi,
    unsigned short* __restrict__ olo) {
  __shared__ int kls[J2];
  __shared__ float4v wls[J2];
  __shared__ float4v part[4][4][64];
  int blk = blockIdx.x;
  int tile = blk >> 3, h = blk & 7;
  int tid = threadIdx.x, g = tid & 63, s = tid >> 6;
  int cnt = kcnt2[tile];
  for (int j = tid; j < cnt; j += 256) {
    kls[j] = klist2[(size_t)tile * J2 + j];
    wls[j] = *(const float4v*)&wlist2[(((size_t)h * 256 + tile) * J2 + j) * 4];
  }
  __syncthreads();
  const float* vb = value + (size_t)h * NK * 256 + g * 4;
  float4v acc[4];
#pragma unroll
  for (int i = 0; i < 4; ++i) acc[i] = (float4v)0.0f;
  for (int j = s; j < cnt; j += 4) {
    int row = kls[j];
    float4v v = *(const float4v*)(vb + (size_t)row * 256);
    float4v w = wls[j];
    acc[0] += w.x * v;
    acc[1] += w.y * v;
    acc[2] += w.z * v;
    acc[3] += w.w * v;
  }
#pragma unroll
  for (int i = 0; i < 4; ++i) part[s][i][g] = acc[i];
  __syncthreads();
  if (tid < 64) {
    int g2 = tid;
    int ttx = tile & 15, tty = tile >> 4;
    int batch = g2 >> 3, v0 = (g2 & 7) * 4;
#pragma unroll
    for (int i = 0; i < 4; ++i) {
      float4v o4 = part[0][i][g2] + part[1][i][g2] + part[2][i][g2] +
                   part[3][i][g2];
      int q = (2 * tty + (i >> 1)) * 32 + 2 * ttx + (i & 1);
      size_t idx = ((size_t)batch * 1024 + q) * 256 + h * 32 + v0;
      ushort4v hv, lv;
#pragma unroll
      for (int c = 0; c < 4; ++c) {
        float oo = gelu_f(o4[c]);
        unsigned short hi, lo;
        split_bf(oo, hi, lo);
        hv[c] = hi; lv[c] = lo;
      }
      *(ushort4v*)(ohi + idx) = hv;
      *(ushort4v*)(olo + idx) = lv;
    }
  }
}

// ---------------------------------------------------------------------------
// Split-bf16 MFMA GEMM, 128x128 tile (big GEMMs, M=32768).
// ---------------------------------------------------------------------------
template <bool DUAL, int OL, bool GEL, bool OHILO>
__global__ __launch_bounds__(256) void k_mf(
    const unsigned short* __restrict__ A1hi, const unsigned short* __restrict__ A1lo,
    const unsigned short* __restrict__ W1hi, const unsigned short* __restrict__ W1lo,
    const unsigned short* __restrict__ A2hi, const unsigned short* __restrict__ A2lo,
    const unsigned short* __restrict__ W2hi, const unsigned short* __restrict__ W2lo,
    const float* __restrict__ bias, const float* __restrict__ bias2,
    float* __restrict__ outf, unsigned short* __restrict__ ohi,
    unsigned short* __restrict__ olo, int NS) {
  __shared__ unsigned short Ah[128][40], Al[128][40];
  __shared__ unsigned short Bh[128][40], Bl[128][40];
  int tid = threadIdx.x;
  int m0 = blockIdx.x * 128, n0 = blockIdx.y * 128;
  int w = tid >> 6, lane = tid & 63;
  int wm = (w >> 1) * 64, wn = (w & 1) * 64;
  int quad = lane >> 4, l16 = lane & 15;
  float4v acc[4][4];
#pragma unroll
  for (int i = 0; i < 4; ++i)
#pragma unroll
    for (int j = 0; j < 4; ++j) acc[i][j] = (float4v)0.0f;

  int srow = tid >> 1, skq = (tid & 1) * 16;
  const int KT = DUAL ? 512 : 256;
  for (int kk = 0; kk < KT; kk += 32) {
    const unsigned short *pAh, *pAl, *pWh, *pWl;
    int kb;
    if (DUAL && kk >= 256) {
      pAh = A2hi; pAl = A2lo; pWh = W2hi; pWl = W2lo; kb = kk - 256;
    } else {
      pAh = A1hi; pAl = A1lo; pWh = W1hi; pWl = W1lo; kb = kk;
    }
    {
      size_t ga = (size_t)(m0 + srow) * 256 + kb + skq;
      const uint4* pah = (const uint4*)(pAh + ga);
      const uint4* pal = (const uint4*)(pAl + ga);
      *(uint4*)&Ah[srow][skq] = pah[0];
      *(uint4*)&Ah[srow][skq + 8] = pah[1];
      *(uint4*)&Al[srow][skq] = pal[0];
      *(uint4*)&Al[srow][skq + 8] = pal[1];
      size_t gb = (size_t)(n0 + srow) * 256 + kb + skq;
      const uint4* pbh = (const uint4*)(pWh + gb);
      const uint4* pbl = (const uint4*)(pWl + gb);
      *(uint4*)&Bh[srow][skq] = pbh[0];
      *(uint4*)&Bh[srow][skq + 8] = pbh[1];
      *(uint4*)&Bl[srow][skq] = pbl[0];
      *(uint4*)&Bl[srow][skq + 8] = pbl[1];
    }
    __syncthreads();
    short8 ah[4], al[4], bh[4], bl[4];
#pragma unroll
    for (int s = 0; s < 4; ++s) {
      ah[s] = *(const short8*)&Ah[wm + s * 16 + l16][quad * 8];
      al[s] = *(const short8*)&Al[wm + s * 16 + l16][quad * 8];
      bh[s] = *(const short8*)&Bh[wn + s * 16 + l16][quad * 8];
      bl[s] = *(const short8*)&Bl[wn + s * 16 + l16][quad * 8];
    }
#pragma unroll
    for (int ms = 0; ms < 4; ++ms)
#pragma unroll
      for (int ns = 0; ns < 4; ++ns) {
        acc[ms][ns] = __builtin_amdgcn_mfma_f32_16x16x32_bf16(
            ah[ms], bh[ns], acc[ms][ns], 0, 0, 0);
        acc[ms][ns] = __builtin_amdgcn_mfma_f32_16x16x32_bf16(
            ah[ms], bl[ns], acc[ms][ns], 0, 0, 0);
        acc[ms][ns] = __builtin_amdgcn_mfma_f32_16x16x32_bf16(
            al[ms], bh[ns], acc[ms][ns], 0, 0, 0);
      }
    __syncthreads();
  }
#pragma unroll
  for (int ms = 0; ms < 4; ++ms) {
#pragma unroll
    for (int ns = 0; ns < 4; ++ns) {
      int n = n0 + wn + ns * 16 + l16;
      float bv = bias ? bias[n] : 0.0f;
      if (DUAL && bias2) bv += bias2[n];
#pragma unroll
      for (int r = 0; r < 4; ++r) {
        int m = m0 + wm + ms * 16 + quad * 4 + r;
        float c = acc[ms][ns][r] + bv;
        if (GEL) c = gelu_f(c);
        if (OHILO) {
          unsigned short chi, clo;
          split_bf(c, chi, clo);
          ohi[(size_t)m * 256 + n] = chi;
          olo[(size_t)m * 256 + n] = clo;
        } else if (OL == 0) {
          outf[(size_t)m * 256 + n] = c;
        } else {
          int N = 1 << NS;
          int bb = m >> NS, rr = m & (N - 1);
          outf[(((size_t)(n >> 5) * N + rr) * 8 + bb) * 32 + (n & 31)] = c;
        }
      }
    }
  }
}

// ---------------------------------------------------------------------------
// Split-bf16 MFMA GEMM, 64x64 tile (medium GEMMs, M=8192 -> 512 blocks).
// ---------------------------------------------------------------------------
template <bool DUAL, int OL, bool GEL, bool OHILO>
__global__ __launch_bounds__(256) void k_mf2(
    const unsigned short* __restrict__ A1hi, const unsigned short* __restrict__ A1lo,
    const unsigned short* __restrict__ W1hi, const unsigned short* __restrict__ W1lo,
    const unsigned short* __restrict__ A2hi, const unsigned short* __restrict__ A2lo,
    const unsigned short* __restrict__ W2hi, const unsigned short* __restrict__ W2lo,
    const float* __restrict__ bias, const float* __restrict__ bias2,
    float* __restrict__ outf, unsigned short* __restrict__ ohi,
    unsigned short* __restrict__ olo, int NS) {
  __shared__ unsigned short Ah[64][40], Al[64][40];
  __shared__ unsigned short Bh[64][40], Bl[64][40];
  int tid = threadIdx.x;
  int m0 = blockIdx.x * 64, n0 = blockIdx.y * 64;
  int w = tid >> 6, lane = tid & 63;
  int wm = (w >> 1) * 32, wn = (w & 1) * 32;
  int quad = lane >> 4, l16 = lane & 15;
  float4v acc[2][2];
#pragma unroll
  for (int i = 0; i < 2; ++i)
#pragma unroll
    for (int j = 0; j < 2; ++j) acc[i][j] = (float4v)0.0f;

  int srow = tid >> 2, skq = (tid & 3) * 8;
  const int KT = DUAL ? 512 : 256;
  for (int kk = 0; kk < KT; kk += 32) {
    const unsigned short *pAh, *pAl, *pWh, *pWl;
    int kb;
    if (DUAL && kk >= 256) {
      pAh = A2hi; pAl = A2lo; pWh = W2hi; pWl = W2lo; kb = kk - 256;
    } else {
      pAh = A1hi; pAl = A1lo; pWh = W1hi; pWl = W1lo; kb = kk;
    }
    {
      size_t ga = (size_t)(m0 + srow) * 256 + kb + skq;
      *(uint4*)&Ah[srow][skq] = *(const uint4*)(pAh + ga);
      *(uint4*)&Al[srow][skq] = *(const uint4*)(pAl + ga);
      size_t gb = (size_t)(n0 + srow) * 256 + kb + skq;
      *(uint4*)&Bh[srow][skq] = *(const uint4*)(pWh + gb);
      *(uint4*)&Bl[srow][skq] = *(const uint4*)(pWl + gb);
    }
    __syncthreads();
    short8 ah[2], al[2], bh[2], bl[2];
#pragma unroll
    for (int s = 0; s < 2; ++s) {
      ah[s] = *(const short8*)&Ah[wm + s * 16 + l16][quad * 8];
      al[s] = *(const short8*)&Al[wm + s * 16 + l16][quad * 8];
      bh[s] = *(const short8*)&Bh[wn + s * 16 + l16][quad * 8];
      bl[s] = *(const short8*)&Bl[wn + s * 16 + l16][quad * 8];
    }
#pragma unroll
    for (int ms = 0; ms < 2; ++ms)
#pragma unroll
      for (int ns = 0; ns < 2; ++ns) {
        acc[ms][ns] = __builtin_amdgcn_mfma_f32_16x16x32_bf16(
            ah[ms], bh[ns], acc[ms][ns], 0, 0, 0);
        acc[ms][ns] = __builtin_amdgcn_mfma_f32_16x16x32_bf16(
            ah[ms], bl[ns], acc[ms][ns], 0, 0, 0);
        acc[ms][ns] = __builtin_amdgcn_mfma_f32_16x16x32_bf16(
            al[ms], bh[ns], acc[ms][ns], 0, 0, 0);
      }
    __syncthreads();
  }
#pragma unroll
  for (int ms = 0; ms < 2; ++ms) {
#pragma unroll
    for (int ns = 0; ns < 2; ++ns) {
      int n = n0 + wn + ns * 16 + l16;
      float bv = bias ? bias[n] : 0.0f;
      if (DUAL && bias2) bv += bias2[n];
#pragma unroll
      for (int r = 0; r < 4; ++r) {
        int m = m0 + wm + ms * 16 + quad * 4 + r;
        float c = acc[ms][ns][r] + bv;
        if (GEL) c = gelu_f(c);
        if (OHILO) {
          unsigned short chi, clo;
          split_bf(c, chi, clo);
          ohi[(size_t)m * 256 + n] = chi;
          olo[(size_t)m * 256 + n] = clo;
        } else if (OL == 0) {
          outf[(size_t)m * 256 + n] = c;
        } else {
          int N = 1 << NS;
          int bb = m >> NS, rr = m & (N - 1);
          outf[(((size_t)(n >> 5) * N + rr) * 8 + bb) * 32 + (n & 31)] = c;
        }
      }
    }
  }
}

// ---------------------------------------------------------------------------
// Separable up-attention stage 1: T[h][qx][ky][bv] = sum_kx Ax[qx][kx]*V.
// ---------------------------------------------------------------------------
__global__ __launch_bounds__(256) void k_up_s1(
    const float* __restrict__ value,  // [h][1024][bv]
    const float* __restrict__ rvec, float* __restrict__ T) {
  __shared__ float AxL[64][33];
  int ky = blockIdx.x, h = blockIdx.y, tid = threadIdx.x;
  float sc = head_scale(rvec[h]) * (1.0f / 8192.0f);
  float v[32];
  const float* vb = value + ((size_t)h * 1024 + ky * 32) * 256 + tid;
#pragma unroll
  for (int kx = 0; kx < 32; ++kx) v[kx] = vb[kx * 256];
  if (tid < 64) {
    int qx = tid, dxmin = qx & 1;
    for (int kx = 0; kx < 32; ++kx) {
      int dx = qx - 2 * kx;
      AxL[qx][kx] = __expf(-sc * (float)(dx * dx - dxmin));
    }
  }
  __syncthreads();
  float* tb = T + (((size_t)h * 64) * 32 + ky) * 256 + tid;
  for (int qx = 0; qx < 64; ++qx) {
    float acc = 0.f;
#pragma unroll
    for (int kx = 0; kx < 32; ++kx) acc += AxL[qx][kx] * v[kx];
    tb[(size_t)qx * 32 * 256] = acc;
  }
}

// ---------------------------------------------------------------------------
// Separable up-attention stage 2 -> bf16 hi/lo (feeds dec-fc1 MFMA).
// ---------------------------------------------------------------------------
__global__ __launch_bounds__(256) void k_up_s2(
    const float* __restrict__ T, const float* __restrict__ rvec,
    unsigned short* __restrict__ ohi, unsigned short* __restrict__ olo) {
  __shared__ float AyL[64][33];
  __shared__ float Sy[64];
  __shared__ float SxS;
  int qx = blockIdx.x, h = blockIdx.y, tid = threadIdx.x;
  float sc = head_scale(rvec[h]) * (1.0f / 8192.0f);
  float t[32];
  const float* tb = T + ((size_t)h * 64 + qx) * 32 * 256 + tid;
#pragma unroll
  for (int ky = 0; ky < 32; ++ky) t[ky] = tb[ky * 256];
  if (tid < 64) {
    int qy = tid, dymin = qy & 1;
    float s = 0.f;
    for (int ky = 0; ky < 32; ++ky) {
      int dy = qy - 2 * ky;
      float e = __expf(-sc * (float)(dy * dy - dymin));
      AyL[qy][ky] = e;
      s += e;
    }
    Sy[qy] = s;
  } else if (tid >= 64 && tid < 96) {
    int kx = tid - 64, dxmin = qx & 1;
    int dx = qx - 2 * kx;
    float e = __expf(-sc * (float)(dx * dx - dxmin));
#pragma unroll
    for (int off = 16; off > 0; off >>= 1) e += __shfl_down(e, off, 32);
    if (kx == 0) SxS = e;
  }
  __syncthreads();
  float invSx = 1.0f / SxS;
  int b = tid >> 5, v = tid & 31;
  size_t base = ((size_t)b * 4096 + qx) * 256 + h * 32 + v;
  for (int qy = 0; qy < 64; ++qy) {
    float acc = 0.f;
#pragma unroll
    for (int ky = 0; ky < 32; ++ky) acc += AyL[qy][ky] * t[ky];
    float o = gelu_f(acc * invSx / Sy[qy]);
    unsigned short hi, lo;
    split_bf(o, hi, lo);
    size_t idx = base + (size_t)qy * 64 * 256;
    ohi[idx] = hi;
    olo[idx] = lo;
  }
}

// ---------------------------------------------------------------------------
__global__ __launch_bounds__(256) void k_fc2(const float* __restrict__ h,
                                             const float* __restrict__ w,
                                             const float* __restrict__ b,
                                             float* __restrict__ out) {
  int row = blockIdx.x * 4 + (threadIdx.x >> 6);
  int lane = threadIdx.x & 63;
  float4 hv = *(const float4*)(h + (size_t)row * 256 + lane * 4);
  float4 wv = *(const float4*)(w + lane * 4);
  float s = hv.x * wv.x + hv.y * wv.y + hv.z * wv.z + hv.w * wv.w;
#pragma unroll
  for (int off = 32; off > 0; off >>= 1) s += __shfl_down(s, off, 64);
  if (lane == 0) out[row] = s + b[0];
}

// ---------------------------------------------------------------------------
extern "C" void kernel_launch(void* const* d_in, const int* in_sizes, int n_in,
                              void* d_out, int out_size, void* d_ws,
                              size_t ws_size, hipStream_t stream) {
  const float* x      = (const float*)d_in[0];
  const float* en_w   = (const float*)d_in[1];
  const float* en_b   = (const float*)d_in[2];
  const float* down_r = (const float*)d_in[3];
  const float* down_w = (const float*)d_in[4];
  const float* pa_r   = (const float*)d_in[5];
  const float* pa_w   = (const float*)d_in[6];
  const float* mlp1_w = (const float*)d_in[7];
  const float* mlp1_b = (const float*)d_in[8];
  const float* mlp2_w = (const float*)d_in[9];
  const float* mlp2_b = (const float*)d_in[10];
  const float* res_w  = (const float*)d_in[11];
  const float* res_b  = (const float*)d_in[12];
  const float* up_r   = (const float*)d_in[13];
  const float* up_w   = (const float*)d_in[14];
  const float* de1_w  = (const float*)d_in[15];
  const float* de1_b  = (const float*)d_in[16];
  const float* de2_w  = (const float*)d_in[17];
  const float* de2_b  = (const float*)d_in[18];
  float* out = (float*)d_out;

  constexpr int J2 = 256;
  float* ws = (float*)d_ws;
  // [0, 8388608): enc / up_s2 activations, bf16 hi/lo (32768x256 each)
  unsigned short* Ahi = (unsigned short*)ws;
  unsigned short* Alo = Ahi + 8388608;
  // [8388608, 16777216): B fp32 — down value / proc+up value / T / dec hidden
  float* B = ws + 8388608;
  float* Tbuf = B + 2097152;
  // [16777216, 25165824): 8 activation hi/lo buffers, each 2097152 ushorts
  // (= 1048576 floats): hAhi hAlo hBhi hBlo pahi palo m1hi m1lo.
  unsigned short* hAhi = (unsigned short*)(ws + 16777216);
  unsigned short* hAlo = hAhi + 2097152;
  unsigned short* hBhi = hAlo + 2097152;
  unsigned short* hBlo = hBhi + 2097152;
  unsigned short* pahi = hBlo + 2097152;
  unsigned short* palo = pahi + 2097152;
  unsigned short* m1hi = palo + 2097152;
  unsigned short* m1lo = m1hi + 2097152;
  // [25165824, ...): misc — AFTER all activation buffers (R8 crash fix).
  int* thrD = (int*)(ws + 25165824);
  int* thrP = thrD + 1024;
  int* cntD2 = thrP + 1024;
  int* cntP2 = cntD2 + 256;
  int* klD2 = cntP2 + 256;              // [256*J2]
  int* klP2 = klD2 + 256 * J2;
  float* wlD2 = (float*)(klP2 + 256 * J2);  // [8*256*J2*4] = 2097152 floats
  float* wlP2 = wlD2 + 2097152;
  unsigned short* Whi = (unsigned short*)(wlP2 + 2097152);  // 1245184 each
  unsigned short* Wlo = Whi + 1245184;
  const int WO_DOWN = 0, WO_DE1 = 65536, WO_UP = 131072, WO_PA = 196608,
            WO_MLP1 = 458752, WO_MLP2 = 720896, WO_RES = 983040;

  // 1. encoder -> bf16 hi/lo
  k_enc<<<32768, 256, 0, stream>>>(x, en_w, en_b, Ahi, Alo);
  // 2. weight splits + thresholds + tiled key lists (input-independent)
  k_split_all<<<4864, 256, 0, stream>>>(down_w, de1_w, up_w, pa_w, mlp1_w,
                                        mlp2_w, res_w, Whi, Wlo);
  k_thresh<64, 2, 16, 82, 7938><<<1024, 256, 0, stream>>>(thrD);
  k_thresh<32, 1, 4, 103, 1922><<<1024, 256, 0, stream>>>(thrP);
  k_klist2<64, 2, 13, J2><<<256, 256, 0, stream>>>(down_r, thrD, klD2, cntD2,
                                                   wlD2);
  k_klist2<32, 1, 11, J2><<<256, 256, 0, stream>>>(pa_r, thrP, klP2, cntP2,
                                                   wlP2);
  // 3. down: value MFMA -> B [h][4096][bv]; tiled sparse att -> hA (hi/lo)
  k_mf<false, 1, false, false><<<dim3(256, 2), 256, 0, stream>>>(
      Ahi, Alo, Whi + WO_DOWN, Wlo + WO_DOWN, nullptr, nullptr, nullptr,
      nullptr, nullptr, nullptr, B, nullptr, nullptr, 12);
  k_att3<4096, J2><<<2048, 256, 0, stream>>>(B, klD2, cntD2, wlD2, hAhi, hAlo);
  // 4. processor blocks, h ping-pong hA <-> hB (64x64-tile MFMA)
  for (int i = 0; i < 4; ++i) {
    const unsigned short* hih = (i & 1) ? hBhi : hAhi;
    const unsigned short* hil = (i & 1) ? hBlo : hAlo;
    unsigned short* hoh = (i & 1) ? hAhi : hBhi;
    unsigned short* hol = (i & 1) ? hAlo : hBlo;
    k_mf2<false, 1, false, false><<<dim3(128, 4), 256, 0, stream>>>(
        hih, hil, Whi + WO_PA + i * 65536, Wlo + WO_PA + i * 65536, nullptr,
        nullptr, nullptr, nullptr, nullptr, nullptr, B, nullptr, nullptr, 10);
    k_att3<1024, J2><<<2048, 256, 0, stream>>>(B, klP2, cntP2, wlP2, pahi,
                                               palo);
    k_mf2<false, 0, true, true><<<dim3(128, 4), 256, 0, stream>>>(
        pahi, palo, Whi + WO_MLP1 + i * 65536, Wlo + WO_MLP1 + i * 65536,
        nullptr, nullptr, nullptr, nullptr, mlp1_b + i * 256, nullptr, nullptr,
        m1hi, m1lo, 0);
    k_mf2<true, 0, true, true><<<dim3(128, 4), 256, 0, stream>>>(
        m1hi, m1lo, Whi + WO_MLP2 + i * 65536, Wlo + WO_MLP2 + i * 65536, hih,
        hil, Whi + WO_RES + i * 65536, Wlo + WO_RES + i * 65536,
        mlp2_b + i * 256, res_b + i * 256, nullptr, hoh, hol, 0);
  }
  // 5. up: value MFMA -> B [h][1024][bv]; separable attention
  k_mf2<false, 1, false, false><<<dim3(128, 4), 256, 0, stream>>>(
      hAhi, hAlo, Whi + WO_UP, Wlo + WO_UP, nullptr, nullptr, nullptr, nullptr,
      nullptr, nullptr, B, nullptr, nullptr, 10);
  k_up_s1<<<dim3(32, 8), 256, 0, stream>>>(B, up_r, Tbuf);
  k_up_s2<<<dim3(64, 8), 256, 0, stream>>>(Tbuf, up_r, Ahi, Alo);
  // 6. decoder: fc1 MFMA -> B fp32; fc2 reduction
  k_mf<false, 0, true, false><<<dim3(256, 2), 256, 0, stream>>>(
      Ahi, Alo, Whi + WO_DE1, Wlo + WO_DE1, nullptr, nullptr, nullptr, nullptr,
      de1_b, nullptr, B, nullptr, nullptr, 0);
  k_fc2<<<8192, 256, 0, stream>>>(B, de2_w, de2_b, out);
}